// Round 7
// baseline (617.021 us; speedup 1.0000x reference)
//
#include <hip/hip_runtime.h>

// Problem constants: b=2, n=8192, DIM=512, HEADS=8, DIM_HEAD=64, M_LAND=256,
// l=32 landmark groups, KS=33. pad==0 and mask all-true -> masking dead code.
// qkv is stored FUSED as (b*n, 1536) bf16 rows (q|k|v interleaved per token):
// row stride 1536; head h occupies cols part*512 + h*64 .. +64.

typedef __attribute__((ext_vector_type(8))) short bf16x8;
typedef __attribute__((ext_vector_type(4))) float f32x4;

static __device__ __forceinline__ ushort f2bf(float f) {
  union { float f; unsigned u; } c; c.f = f;
  const unsigned r = c.u + 0x7fffu + ((c.u >> 16) & 1u);
  return (ushort)(r >> 16);
}
static __device__ __forceinline__ float bf2f(ushort u) {
  union { unsigned u; float f; } c; c.u = ((unsigned)u) << 16;
  return c.f;
}

// async global->LDS, 16B per lane. LDS dest is wave-uniform base + lane*16.
typedef __attribute__((address_space(1))) const unsigned int guint;
typedef __attribute__((address_space(3))) unsigned int luint;
static __device__ __forceinline__ void gload_lds16(const void* g, void* l) {
  __builtin_amdgcn_global_load_lds((guint*)g, (luint*)l, 16, 0, 0);
}

// ---------------- LayerNorm: one block per row of 512, bf16 output ----------------
__global__ __launch_bounds__(256) void ln_kernel(const float* __restrict__ x,
                                                 const float* __restrict__ w,
                                                 const float* __restrict__ b,
                                                 ushort* __restrict__ xn) {
  const int row = blockIdx.x;
  const int t = threadIdx.x;
  const float* xr = x + (long long)row * 512;
  float v0 = xr[t], v1 = xr[t + 256];
  __shared__ float red[8];
  float s = v0 + v1;
#pragma unroll
  for (int o = 32; o; o >>= 1) s += __shfl_xor(s, o);
  if ((t & 63) == 0) red[t >> 6] = s;
  __syncthreads();
  const float mu = (red[0] + red[1] + red[2] + red[3]) * (1.0f / 512.0f);
  const float d0 = v0 - mu, d1 = v1 - mu;
  float qs = d0 * d0 + d1 * d1;
#pragma unroll
  for (int o = 32; o; o >>= 1) qs += __shfl_xor(qs, o);
  if ((t & 63) == 0) red[4 + (t >> 6)] = qs;
  __syncthreads();
  const float var = (red[4] + red[5] + red[6] + red[7]) * (1.0f / 512.0f);
  const float rs = rsqrtf(var + 1e-5f);
  ushort* xo = xn + (long long)row * 512;
  xo[t] = f2bf(d0 * rs * w[t] + b[t]);
  xo[t + 256] = f2bf(d1 * rs * w[t + 256] + b[t + 256]);
}

// ------------- transpose + convert fp32 [R][Cc] -> bf16 [Cc][R] -------------
__global__ __launch_bounds__(256) void convert_T_bf16(const float* __restrict__ in,
                                                      ushort* __restrict__ out,
                                                      int R, int Cc) {
  const long long i = (long long)blockIdx.x * 256 + threadIdx.x;
  if (i >= (long long)R * Cc) return;
  const int c = (int)(i / R), r = (int)(i % R);
  out[i] = f2bf(in[(long long)r * Cc + c]);
}

// ---------------- bf16 MFMA GEMM: C = A @ Bt^T  (m97 structure) ----------------
// global_load_lds width-16 staging into linear LDS [128][32], 2 barriers/K-step.
// XCD-bijective block swizzle (requires nwg % 8 == 0; holds: 1536 and 512).
// mode 2: qkv fused output (b*n, 1536) bf16, q-part (cols<512) x0.125
// mode 3: C[r*512+c] = acc + bias[c] + xres[r*512+c]  (fp32)
__global__ __launch_bounds__(256) void gemm_bf16(
    const ushort* __restrict__ A, const ushort* __restrict__ Bt,
    float* __restrict__ C, ushort* __restrict__ uq,
    const float* __restrict__ bias, const float* __restrict__ xres,
    int K, int mode) {
  const int tid = threadIdx.x;
  const int wave = tid >> 6, lane = tid & 63;
  const int quad = lane >> 4, l16 = lane & 15;

  // XCD swizzle: consecutive work-ids (sharing an A-panel) land on ONE XCD's L2.
  const int gx = gridDim.x;
  const int nwg = gx * gridDim.y;
  const int hid = blockIdx.y * gx + blockIdx.x;
  const int wid = (hid & 7) * (nwg >> 3) + (hid >> 3);
  const int tm = (wid / gx) * 128, tn = (wid % gx) * 128;

  const int wr = (wave >> 1) * 64, wc = (wave & 1) * 64;
  __shared__ __align__(16) ushort As[128 * 32];
  __shared__ __align__(16) ushort Bs[128 * 32];

  f32x4 acc[4][4];
#pragma unroll
  for (int i = 0; i < 4; ++i)
#pragma unroll
    for (int j = 0; j < 4; ++j) acc[i][j] = (f32x4)0.f;

  // staging: chunk i = call*256 + tid; row = i>>2; col-chunk = (i&3)*8 ushorts
  const int r0 = tid >> 2;
  const int c0 = (tid & 3) * 8;
  const ushort* gA0 = A + (long long)(tm + r0) * K + c0;
  const ushort* gA1 = A + (long long)(tm + 64 + r0) * K + c0;
  const ushort* gB0 = Bt + (long long)(tn + r0) * K + c0;
  const ushort* gB1 = Bt + (long long)(tn + 64 + r0) * K + c0;
  ushort* lA0 = As + (wave * 64) * 8;          // wave-uniform LDS bases
  ushort* lA1 = As + (256 + wave * 64) * 8;
  ushort* lB0 = Bs + (wave * 64) * 8;
  ushort* lB1 = Bs + (256 + wave * 64) * 8;

  for (int kb = 0; kb < K; kb += 32) {
    __syncthreads();
    gload_lds16(gA0 + kb, lA0);
    gload_lds16(gA1 + kb, lA1);
    gload_lds16(gB0 + kb, lB0);
    gload_lds16(gB1 + kb, lB1);
    __syncthreads();
    bf16x8 af[4], bfr[4];
#pragma unroll
    for (int t = 0; t < 4; ++t) {
      af[t] = *(const bf16x8*)&As[(wr + t * 16 + l16) * 32 + quad * 8];
      bfr[t] = *(const bf16x8*)&Bs[(wc + t * 16 + l16) * 32 + quad * 8];
    }
#pragma unroll
    for (int i = 0; i < 4; ++i)
#pragma unroll
      for (int j = 0; j < 4; ++j)
        acc[i][j] = __builtin_amdgcn_mfma_f32_16x16x32_bf16(af[i], bfr[j], acc[i][j], 0, 0, 0);
  }

  if (mode == 2) {  // fused (b*n,1536) layout: plain row-major store, no scatter
    const float scale = ((tn + wc) >> 9) == 0 ? 0.125f : 1.0f;  // q * 8^-0.5... DIM_HEAD^-0.5
#pragma unroll
    for (int ti = 0; ti < 4; ++ti) {
#pragma unroll
      for (int r = 0; r < 4; ++r) {
        const int gr = tm + wr + ti * 16 + quad * 4 + r;
        ushort* drow = uq + (long long)gr * 1536 + tn + wc;
#pragma unroll
        for (int tj = 0; tj < 4; ++tj)
          drow[tj * 16 + l16] = f2bf(acc[ti][tj][r] * scale);
      }
    }
  } else {  // mode 3
#pragma unroll
    for (int ti = 0; ti < 4; ++ti) {
#pragma unroll
      for (int r = 0; r < 4; ++r) {
        const long long gr = tm + wr + ti * 16 + quad * 4 + r;
#pragma unroll
        for (int tj = 0; tj < 4; ++tj) {
          const int gc = tn + wc + tj * 16 + l16;
          const long long idx = gr * 512 + gc;
          C[idx] = acc[ti][tj][r] + bias[gc] + xres[idx];
        }
      }
    }
  }
}

// ---------------- fp32 GEMM (sim2 only): C = A@B ----------------
__global__ __launch_bounds__(256) void gemm_f32(
    const float* __restrict__ A, const float* __restrict__ B,
    float* __restrict__ C, int K, int lda, int ldb, int ldc,
    long long sA, long long sB, long long sC) {
  const int tid = threadIdx.x;
  const int batch = blockIdx.z;
  A += (long long)batch * sA;
  B += (long long)batch * sB;
  C += (long long)batch * sC;
  const int tm = blockIdx.y * 64;
  const int tn = blockIdx.x * 64;

  __shared__ float As[16][65];
  __shared__ float Bs[16][65];

  const int tx = tid & 15, ty = tid >> 4;
  const int ar = tid >> 2, ac = (tid & 3) * 4;
  const int br = tid >> 4, bc = (tid & 15) * 4;

  float acc[4][4];
#pragma unroll
  for (int i = 0; i < 4; ++i)
#pragma unroll
    for (int j = 0; j < 4; ++j) acc[i][j] = 0.f;

  for (int kb = 0; kb < K; kb += 16) {
    const float4 a4 = *(const float4*)(A + (long long)(tm + ar) * lda + kb + ac);
    const float4 b4 = *(const float4*)(B + (long long)(kb + br) * ldb + tn + bc);
    __syncthreads();
    As[ac + 0][ar] = a4.x; As[ac + 1][ar] = a4.y;
    As[ac + 2][ar] = a4.z; As[ac + 3][ar] = a4.w;
    Bs[br][bc + 0] = b4.x; Bs[br][bc + 1] = b4.y;
    Bs[br][bc + 2] = b4.z; Bs[br][bc + 3] = b4.w;
    __syncthreads();
#pragma unroll
    for (int kk = 0; kk < 16; ++kk) {
      float av[4], bv[4];
#pragma unroll
      for (int i = 0; i < 4; ++i) av[i] = As[kk][ty * 4 + i];
#pragma unroll
      for (int j = 0; j < 4; ++j) bv[j] = Bs[kk][tx * 4 + j];
#pragma unroll
      for (int i = 0; i < 4; ++i)
#pragma unroll
        for (int j = 0; j < 4; ++j) acc[i][j] = fmaf(av[i], bv[j], acc[i][j]);
    }
  }
#pragma unroll
  for (int i = 0; i < 4; ++i) {
    const long long r = tm + ty * 4 + i;
#pragma unroll
    for (int j = 0; j < 4; ++j) C[r * ldc + tn + tx * 4 + j] = acc[i][j];
  }
}

// -------- split/hi bf16 MFMA batched GEMM stage body for the pinv chain --------
static __device__ __forceinline__ void stage_body(
    int tc, int tr, int bh,
    const ushort* __restrict__ Ah, const ushort* __restrict__ Al,
    const ushort* __restrict__ BTh, const ushort* __restrict__ BTl,
    const ushort* __restrict__ D1h, const ushort* __restrict__ D1l,
    const ushort* __restrict__ D2h, const ushort* __restrict__ D2l,
    ushort* __restrict__ Ch, ushort* __restrict__ Cl,
    ushort* __restrict__ CTh, ushort* __restrict__ CTl,
    float alpha, float beta1, float beta2,
    long long sBT, long long sC, int ldc,
    ushort (*TBh)[36], ushort (*TBl)[36]) {
  const int tid = threadIdx.x;
  const int wave = tid >> 6, lane = tid & 63;
  const int quad = lane >> 4, l16 = lane & 15;
  const bool hasAl = (Al != nullptr);
  const bool hasBl = (BTl != nullptr);

  const ushort* A_h = Ah + (long long)bh * 65536 + (long long)(tr + wave * 16 + l16) * 256;
  const ushort* A_l = (hasAl ? Al : Ah) + (long long)bh * 65536 +
                      (long long)(tr + wave * 16 + l16) * 256;
  const ushort* B_h0 = BTh + (long long)bh * sBT + (long long)(tc + l16) * 256;
  const ushort* B_l0 = (hasBl ? BTl : BTh) + (long long)bh * sBT +
                       (long long)(tc + l16) * 256;

  f32x4 acc[2];
  acc[0] = (f32x4)0.f; acc[1] = (f32x4)0.f;

#pragma unroll
  for (int kc = 0; kc < 8; ++kc) {
    const int ko = kc * 32 + quad * 8;
    const bf16x8 a_h = *(const bf16x8*)(A_h + ko);
    bf16x8 a_l;
    if (hasAl) a_l = *(const bf16x8*)(A_l + ko);
#pragma unroll
    for (int ct = 0; ct < 2; ++ct) {
      const bf16x8 b_h = *(const bf16x8*)(B_h0 + ct * 4096 + ko);
      acc[ct] = __builtin_amdgcn_mfma_f32_16x16x32_bf16(a_h, b_h, acc[ct], 0, 0, 0);
      if (hasBl) {
        const bf16x8 b_l = *(const bf16x8*)(B_l0 + ct * 4096 + ko);
        acc[ct] = __builtin_amdgcn_mfma_f32_16x16x32_bf16(a_h, b_l, acc[ct], 0, 0, 0);
      }
      if (hasAl)
        acc[ct] = __builtin_amdgcn_mfma_f32_16x16x32_bf16(a_l, b_h, acc[ct], 0, 0, 0);
    }
  }

#pragma unroll
  for (int ct = 0; ct < 2; ++ct) {
#pragma unroll
    for (int r = 0; r < 4; ++r) {
      const int rl = wave * 16 + quad * 4 + r;
      const int clc = ct * 16 + l16;
      float val = alpha * acc[ct][r];
      if (D1h) {
        const long long di = (long long)bh * 65536 + (long long)(tr + rl) * 256 + tc + clc;
        float d = bf2f(D1h[di]);
        if (D1l) d += bf2f(D1l[di]);
        val += beta1 * d;
      }
      if (D2h) {
        const long long di = (long long)bh * 65536 + (long long)(tr + rl) * 256 + tc + clc;
        float d = bf2f(D2h[di]);
        if (D2l) d += bf2f(D2l[di]);
        val += beta2 * d;
      }
      const ushort h = f2bf(val);
      TBh[rl][clc] = h;
      TBl[rl][clc] = f2bf(val - bf2f(h));
    }
  }
  __syncthreads();
  if (Ch) {  // row-major store, coalesced uint4
    const int rl = tid >> 2, seg = (tid & 3) * 8;
    const long long ci = (long long)bh * sC + (long long)(tr + rl) * ldc + tc + seg;
    *(uint4*)&Ch[ci] = *(const uint4*)&TBh[rl][seg];
    if (Cl) *(uint4*)&Cl[ci] = *(const uint4*)&TBl[rl][seg];
  }
  if (CTh) {  // transposed store: gather 8 from LDS, uint4 out
    const int clc = tid >> 3, seg = (tid & 7) * 8;
    union { uint4 u; ushort s[8]; } th, tl;
#pragma unroll
    for (int j = 0; j < 8; ++j) {
      th.s[j] = TBh[seg + j][clc];
      tl.s[j] = TBl[seg + j][clc];
    }
    const long long gi = (long long)bh * 65536 + (long long)(tc + clc) * 256 + tr + seg;
    *(uint4*)&CTh[gi] = th.u;
    if (CTl) *(uint4*)&CTl[gi] = tl.u;
  }
}

// standard stage kernel: grid (cols/32, rows/64, 16)
__global__ __launch_bounds__(256) void gemm_split(
    const ushort* __restrict__ Ah, const ushort* __restrict__ Al,
    const ushort* __restrict__ BTh, const ushort* __restrict__ BTl,
    const ushort* __restrict__ D1h, const ushort* __restrict__ D1l,
    const ushort* __restrict__ D2h, const ushort* __restrict__ D2l,
    ushort* __restrict__ Ch, ushort* __restrict__ Cl,
    ushort* __restrict__ CTh, ushort* __restrict__ CTl,
    float alpha, float beta1, float beta2,
    long long sBT, long long sC, int ldc) {
  __shared__ ushort TBh[64][36];
  __shared__ ushort TBl[64][36];
  stage_body(blockIdx.x * 32, blockIdx.y * 64, blockIdx.z,
             Ah, Al, BTh, BTl, D1h, D1l, D2h, D2l, Ch, Cl, CTh, CTl,
             alpha, beta1, beta2, sBT, sC, ldc, TBh, TBl);
}

// dual-update kernel: one launch computes BOTH  z' = -0.25 z@T2 + 3.25 z  and
// Y' = -0.25 Y@T2 + 3.25 Y. grid (8, 8, 16): y<4 -> z rows, y>=4 -> Y rows.
__global__ __launch_bounds__(256) void gemm_dual(
    const ushort* __restrict__ zA, const ushort* __restrict__ yA,
    const ushort* __restrict__ BT,
    ushort* __restrict__ zC, ushort* __restrict__ zCT,
    ushort* __restrict__ yC, ushort* __restrict__ yCT) {
  __shared__ ushort TBh[64][36];
  __shared__ ushort TBl[64][36];
  const int by = blockIdx.y;
  if (by < 4)
    stage_body(blockIdx.x * 32, by * 64, blockIdx.z,
               zA, nullptr, BT, nullptr, zA, nullptr, nullptr, nullptr,
               zC, nullptr, zCT, nullptr, -0.25f, 3.25f, 0.f,
               65536, 65536, 256, TBh, TBl);
  else
    stage_body(blockIdx.x * 32, (by - 4) * 64, blockIdx.z,
               yA, nullptr, BT, nullptr, yA, nullptr, nullptr, nullptr,
               yC, nullptr, yCT, nullptr, -0.25f, 3.25f, 0.f,
               65536, 65536, 256, TBh, TBl);
}

// ------------- landmark means from fused qkv -------------
__global__ __launch_bounds__(64) void landmark_kernel(
    const ushort* __restrict__ qkv,
    float* __restrict__ qlf, float* __restrict__ klTf,
    ushort* __restrict__ qlb, ushort* __restrict__ klb) {
  const int bh = blockIdx.y, i = blockIdx.x, d = threadIdx.x;
  const int b = bh >> 3, h = bh & 7;
  const long long rowbase = ((long long)(b * 8192 + i * 32)) * 1536 + h * 64 + d;
  float sq = 0.f, sk = 0.f;
#pragma unroll
  for (int j = 0; j < 32; ++j) {
    sq += bf2f(qkv[rowbase + (long long)j * 1536]);
    sk += bf2f(qkv[rowbase + (long long)j * 1536 + 512]);
  }
  const float mq = sq * (1.0f / 32.0f), mk = sk * (1.0f / 32.0f);
  qlf[((long long)bh * 256 + i) * 64 + d] = mq;
  klTf[((long long)bh * 64 + d) * 256 + i] = mk;
  qlb[((long long)bh * 256 + i) * 64 + d] = f2bf(mq);
  klb[((long long)bh * 256 + i) * 64 + d] = f2bf(mk);
}

// ---------------- softmax over rows of length 256: wave per row ----------------
__global__ __launch_bounds__(256) void softmax256(float* __restrict__ a) {
  const long long row = (long long)blockIdx.x * 4 + (threadIdx.x >> 6);
  const int lane = threadIdx.x & 63;
  float* p = a + row * 256 + lane * 4;
  float4 vv = *(float4*)p;
  float m = fmaxf(fmaxf(vv.x, vv.y), fmaxf(vv.z, vv.w));
#pragma unroll
  for (int o = 32; o; o >>= 1) m = fmaxf(m, __shfl_xor(m, o));
  vv.x = __expf(vv.x - m); vv.y = __expf(vv.y - m);
  vv.z = __expf(vv.z - m); vv.w = __expf(vv.w - m);
  float s = vv.x + vv.y + vv.z + vv.w;
#pragma unroll
  for (int o = 32; o; o >>= 1) s += __shfl_xor(s, o);
  const float inv = 1.0f / s;
  vv.x *= inv; vv.y *= inv; vv.z *= inv; vv.w *= inv;
  *(float4*)p = vv;
}

// ---------------- bf16 MFMA flash attention: Out = softmax(Q K^T) V ----------------
// Generic addressing: base = ptr + (bh>>3)*s + (bh&7)*hS, rows advance by r
// (elements). Compact [bh][N][64] buffers: s=8*N*64, hS=N*64, r=64.
// Fused qkv (b*n,1536): s=8192*1536, hS=64, r=1536 (ptr pre-offset by part*512).
// nsplit==1 && CV==null: writes bf16 to Out (ushort*), sO in elements.
// nsplit==1 && CV!=null: fused epilogue -- adds conv residual CV (b,h,n,d) and
//   writes directly into (b*n, 512) layout at Out (ushort*), col block h*64.
__global__ __launch_bounds__(256) void flash_mfma(
    const ushort* __restrict__ Q, const ushort* __restrict__ K,
    const ushort* __restrict__ V, float* __restrict__ Out,
    const ushort* __restrict__ CV,
    float* __restrict__ Opart, float* __restrict__ Mpart,
    float* __restrict__ Lpart,
    long long sQ, long long hQ, int rQ,
    long long sK, long long hK, int rK,
    long long sV, long long hV, int rV,
    long long sO, int iters, int nsplit) {
  const int bh = blockIdx.z, mt = blockIdx.y, ns = blockIdx.x;
  const int tid = threadIdx.x;
  const int wave = tid >> 6, lane = tid & 63;
  const int quad = lane >> 4, l16 = lane & 15;
  __shared__ ushort Vt[64][72];  // [d][key]
  __shared__ ushort Ps[64][72];  // [q-row][key]

  const ushort* Qb = Q + (bh >> 3) * sQ + (bh & 7) * hQ + (long long)(mt * 64) * rQ;
  const ushort* Kb = K + (bh >> 3) * sK + (bh & 7) * hK + (long long)(ns * iters * 64) * rK;
  const ushort* Vb = V + (bh >> 3) * sV + (bh & 7) * hV + (long long)(ns * iters * 64) * rV;

  bf16x8 aq[2];
#pragma unroll
  for (int kc = 0; kc < 2; ++kc)
    aq[kc] = *(const bf16x8*)(Qb + (long long)(wave * 16 + l16) * rQ + kc * 32 + quad * 8);

  f32x4 acc[4];
  float mrow[4], lrow[4];
#pragma unroll
  for (int dt = 0; dt < 4; ++dt) acc[dt] = (f32x4)0.f;
#pragma unroll
  for (int r = 0; r < 4; ++r) { mrow[r] = -1e30f; lrow[r] = 0.f; }

  for (int it = 0; it < iters; ++it) {
    __syncthreads();
    for (int i = tid; i < 512; i += 256) {
      const int key = i & 63, c8 = (i >> 6) * 8;
      union { uint4 u; ushort s[8]; } t;
      t.u = *(const uint4*)(Vb + (long long)(it * 64 + key) * rV + c8);
#pragma unroll
      for (int j = 0; j < 8; ++j) Vt[c8 + j][key] = t.s[j];
    }
    f32x4 sfr[4];
#pragma unroll
    for (int kt = 0; kt < 4; ++kt) {
      sfr[kt] = (f32x4)0.f;
#pragma unroll
      for (int kc = 0; kc < 2; ++kc) {
        const bf16x8 bk = *(const bf16x8*)(Kb +
            (long long)(it * 64 + kt * 16 + l16) * rK + kc * 32 + quad * 8);
        sfr[kt] = __builtin_amdgcn_mfma_f32_16x16x32_bf16(aq[kc], bk, sfr[kt], 0, 0, 0);
      }
    }
#pragma unroll
    for (int r = 0; r < 4; ++r) {
      float rm = fmaxf(fmaxf(sfr[0][r], sfr[1][r]), fmaxf(sfr[2][r], sfr[3][r]));
#pragma unroll
      for (int off = 1; off < 16; off <<= 1) rm = fmaxf(rm, __shfl_xor(rm, off));
      const float mn = fmaxf(mrow[r], rm);
      const float scv = __expf(mrow[r] - mn);
      float rs = 0.f;
#pragma unroll
      for (int kt = 0; kt < 4; ++kt) {
        const float p = __expf(sfr[kt][r] - mn);
        sfr[kt][r] = p;
        rs += p;
      }
#pragma unroll
      for (int off = 1; off < 16; off <<= 1) rs += __shfl_xor(rs, off);
      lrow[r] = lrow[r] * scv + rs;
      mrow[r] = mn;
#pragma unroll
      for (int dt = 0; dt < 4; ++dt) acc[dt][r] *= scv;
#pragma unroll
      for (int kt = 0; kt < 4; ++kt)
        Ps[wave * 16 + quad * 4 + r][kt * 16 + l16] = f2bf(sfr[kt][r]);
    }
    __syncthreads();
#pragma unroll
    for (int kc = 0; kc < 2; ++kc) {
      const bf16x8 ap = *(const bf16x8*)&Ps[wave * 16 + l16][kc * 32 + quad * 8];
#pragma unroll
      for (int dt = 0; dt < 4; ++dt) {
        const bf16x8 bv = *(const bf16x8*)&Vt[dt * 16 + l16][kc * 32 + quad * 8];
        acc[dt] = __builtin_amdgcn_mfma_f32_16x16x32_bf16(ap, bv, acc[dt], 0, 0, 0);
      }
    }
  }

  if (nsplit == 1) {
    if (CV) {  // fused: add conv residual, write (b*n, 512) layout
      const int b = bh >> 3, h = bh & 7;
      const ushort* cvb = CV + (((long long)bh << 13) + mt * 64) * 64;
      ushort* Ob = (ushort*)Out + ((long long)(b * 8192 + mt * 64)) * 512 + h * 64;
#pragma unroll
      for (int r = 0; r < 4; ++r) {
        const float inv = 1.0f / lrow[r];
        const int row = wave * 16 + quad * 4 + r;
#pragma unroll
        for (int dt = 0; dt < 4; ++dt) {
          const int col = dt * 16 + l16;
          const float val = acc[dt][r] * inv + bf2f(cvb[(long long)row * 64 + col]);
          Ob[(long long)row * 512 + col] = f2bf(val);
        }
      }
    } else {
      ushort* Ob = (ushort*)Out + (long long)bh * sO + (long long)(mt * 64) * 64;
#pragma unroll
      for (int r = 0; r < 4; ++r) {
        const float inv = 1.0f / lrow[r];
        const int row = wave * 16 + quad * 4 + r;
#pragma unroll
        for (int dt = 0; dt < 4; ++dt)
          Ob[(long long)row * 64 + dt * 16 + l16] = f2bf(acc[dt][r] * inv);
      }
    }
  } else {
    const long long pbase = ((long long)(bh * gridDim.y + mt) * nsplit + ns);
    const int row0 = wave * 16 + quad * 4;
#pragma unroll
    for (int r = 0; r < 4; ++r) {
#pragma unroll
      for (int dt = 0; dt < 4; ++dt)
        Opart[(pbase * 64 + row0 + r) * 64 + dt * 16 + l16] = acc[dt][r];
      if (l16 == 0) {
        Mpart[pbase * 64 + row0 + r] = mrow[r];
        Lpart[pbase * 64 + row0 + r] = lrow[r];
      }
    }
  }
}

// ------- merge flash partials -> a3v^T hi/lo bf16 [bh][64][256]; 1024 blocks -------
__global__ __launch_bounds__(256) void flash_merge(
    const float* __restrict__ Opart, const float* __restrict__ Mpart,
    const float* __restrict__ Lpart, ushort* __restrict__ a3vTh,
    ushort* __restrict__ a3vTl, int nsplit) {
  const int bm = blockIdx.x >> 4;  // bh*4 + mt
  const int rg = blockIdx.x & 15;  // 4-row group
  const int bh = bm >> 2, mt = bm & 3;
  const int c = threadIdx.x & 63, rb = threadIdx.x >> 6;
  const int r = rg * 4 + rb;
  float ms = -1e30f;
  for (int ns = 0; ns < nsplit; ++ns)
    ms = fmaxf(ms, Mpart[(bm * nsplit + ns) * 64 + r]);
  float L = 0.f, O = 0.f;
  for (int ns = 0; ns < nsplit; ++ns) {
    const float w = __expf(Mpart[(bm * nsplit + ns) * 64 + r] - ms);
    L += w * Lpart[(bm * nsplit + ns) * 64 + r];
    O += w * Opart[((long long)(bm * nsplit + ns) * 64 + r) * 64 + c];
  }
  const float val = O / L;
  const ushort h = f2bf(val);
  const long long ti = (long long)bh * 16384 + (long long)c * 256 + mt * 64 + r;
  a3vTh[ti] = h;
  a3vTl[ti] = f2bf(val - bf2f(h));
}

// ------- pm init + a2 row/col-sum global maxes (atomicMax on positive floats) -------
__global__ void pm_init(float* __restrict__ pm) {
  if (threadIdx.x < 2) pm[threadIdx.x] = 0.f;
}

__global__ __launch_bounds__(256) void a2_sums(const float* __restrict__ a2,
                                               float* __restrict__ pm) {
  // grid (8, 16): p = 32-row/col slice, bh
  const int p = blockIdx.x, bh = blockIdx.y;
  const float* m = a2 + (long long)bh * 65536;
  const int tid = threadIdx.x;
  __shared__ float red[4];
  {  // row sums: 8 threads per row, 32 elems each
    const int r = p * 32 + (tid >> 3);
    const int c0 = (tid & 7) * 32;
    float s = 0.f;
#pragma unroll 8
    for (int j = 0; j < 32; ++j) s += m[r * 256 + c0 + j];
    s += __shfl_xor(s, 1); s += __shfl_xor(s, 2); s += __shfl_xor(s, 4);
    float mx = s;
#pragma unroll
    for (int o = 8; o < 64; o <<= 1) mx = fmaxf(mx, __shfl_xor(mx, o));
    if ((tid & 63) == 0) red[tid >> 6] = mx;
    __syncthreads();
    if (tid == 0) {
      mx = fmaxf(fmaxf(red[0], red[1]), fmaxf(red[2], red[3]));
      atomicMax((int*)&pm[0], __float_as_int(mx));
    }
    __syncthreads();
  }
  {  // col sums: 8 threads per col, 32 rows each
    const int c = p * 32 + (tid >> 3);
    const int r0 = (tid & 7) * 32;
    float s = 0.f;
#pragma unroll 8
    for (int j = 0; j < 32; ++j) s += m[(r0 + j) * 256 + c];
    s += __shfl_xor(s, 1); s += __shfl_xor(s, 2); s += __shfl_xor(s, 4);
    float mx = s;
#pragma unroll
    for (int o = 8; o < 64; o <<= 1) mx = fmaxf(mx, __shfl_xor(mx, o));
    if ((tid & 63) == 0) red[tid >> 6] = mx;
    __syncthreads();
    if (tid == 0) {
      mx = fmaxf(fmaxf(red[0], red[1]), fmaxf(red[2], red[3]));
      atomicMax((int*)&pm[1], __float_as_int(mx));
    }
  }
}

// ---- pinv init: split a2 -> hi/lo; z0 = a2^T * s (hi row-major + hi transposed) ----
__global__ __launch_bounds__(256) void pinv_init(
    const float* __restrict__ a2, const float* __restrict__ pm,
    ushort* __restrict__ a2h, ushort* __restrict__ a2l,
    ushort* __restrict__ zh, ushort* __restrict__ zTh) {
  const int bh = blockIdx.y;
  const float s = 1.0f / (pm[0] * pm[1]);
  const long long base = (long long)bh * 65536;
  const int i0 = blockIdx.x * 4096;
  for (int t = threadIdx.x; t < 4096; t += 256) {
    const int idx = i0 + t;
    const float v = a2[base + idx];
    const ushort h = f2bf(v);
    a2h[base + idx] = h;
    a2l[base + idx] = f2bf(v - bf2f(h));
    zTh[base + idx] = f2bf(v * s);  // zT = a2 * s
    const float vt = a2[base + ((long long)(idx & 255) << 8) + (idx >> 8)] * s;
    zh[base + idx] = f2bf(vt);
  }
}

// -------- depthwise conv (KS=33) from fused qkv v-part -> cv (bf16, (b,h,n,d)) --------
__global__ __launch_bounds__(256) void conv_store(const ushort* __restrict__ qkv,
                                                  const float* __restrict__ w,
                                                  ushort* __restrict__ cv) {
  const int bh = blockIdx.y;
  const int n0 = blockIdx.x * 128;
  const int b = bh >> 3, h = bh & 7;
  __shared__ float vs[160][64];
  __shared__ float ws[33];
  if (threadIdx.x < 33) ws[threadIdx.x] = w[h * 33 + threadIdx.x];
  for (int i = threadIdx.x; i < 160 * 8; i += 256) {
    const int r = i >> 3, c8 = (i & 7) * 8;
    const int n = n0 - 16 + r;
    if (n >= 0 && n < 8192) {
      union { uint4 u; ushort s[8]; } t;
      t.u = *(const uint4*)(qkv + ((long long)(b * 8192 + n)) * 1536 + 1024 + h * 64 + c8);
#pragma unroll
      for (int j = 0; j < 8; ++j) vs[r][c8 + j] = bf2f(t.s[j]);
    } else {
#pragma unroll
      for (int j = 0; j < 8; ++j) vs[r][c8 + j] = 0.f;
    }
  }
  __syncthreads();
  const int d = threadIdx.x & 63, r0 = threadIdx.x >> 6;
  for (int rr = r0; rr < 128; rr += 4) {
    float acc = 0.f;
#pragma unroll
    for (int kk = 0; kk < 33; ++kk) acc += ws[kk] * vs[rr + kk][d];
    cv[(((long long)bh << 13) + n0 + rr) * 64 + d] = f2bf(acc);
  }
}

// ---------------- host ----------------
static inline void launch_split(hipStream_t st, int gridX,
    const ushort* Ah, const ushort* Al,
    const ushort* BTh, const ushort* BTl, long long sBT,
    const ushort* D1h, const ushort* D1l, float beta1,
    const ushort* D2h, const ushort* D2l, float beta2,
    ushort* Ch, ushort* Cl, ushort* CTh, ushort* CTl,
    long long sC, int ldc, float alpha) {
  dim3 grid((unsigned)gridX, 4, 16);
  hipLaunchKernelGGL(gemm_split, grid, dim3(256), 0, st, Ah, Al, BTh, BTl,
                     D1h, D1l, D2h, D2l, Ch, Cl, CTh, CTl,
                     alpha, beta1, beta2, sBT, sC, ldc);
}

extern "C" void kernel_launch(void* const* d_in, const int* in_sizes, int n_in,
                              void* d_out, int out_size, void* d_ws, size_t ws_size,
                              hipStream_t stream) {
  const float* x = (const float*)d_in[0];
  // d_in[1] = mask: all-true -> unused
  const float* ln_w = (const float*)d_in[2];
  const float* ln_b = (const float*)d_in[3];
  const float* w_qkv = (const float*)d_in[4];
  const float* w_out = (const float*)d_in[5];
  const float* b_out = (const float*)d_in[6];
  const float* conv_w = (const float*)d_in[7];
  float* out = (float*)d_out;

  float* ws = (float*)d_ws;
  // Region R (10,485,760 floats = 40 MB), time-multiplexed:
  //   phase A: Opart/Mpart/Lpart; phase B: pinv chain; phase C: ao2 + cv (bf16)
  float* R = ws;
  float* a2   = R + 10485760LL;        // 1048576 fp32
  float* qlf  = a2 + 1048576LL;        // 262144
  float* klTf = qlf + 262144LL;        // 262144
  float* pm   = klTf + 262144LL;       // 64
  ushort* qkv_bf = (ushort*)(pm + 64); // 25165824 ushorts: fused (b*n,1536)
  ushort* xn_bf  = qkv_bf + 25165824LL;
  ushort* ql_bf  = xn_bf + 8388608LL;  // 262144
  ushort* kl_bf  = ql_bf + 262144LL;
  ushort* tb_bf  = kl_bf + 262144LL;   // 262144
  ushort* wqT_bf = tb_bf + 262144LL;   // 786432
  ushort* woT_bf = wqT_bf + 786432LL;  // 262144
  ushort* a2h    = woT_bf + 262144LL;  // 1048576 each
  ushort* a2l    = a2h + 1048576LL;
  ushort* a3vTh  = a2l + 1048576LL;    // 262144 each
  ushort* a3vTl  = a3vTh + 262144LL;

  // phase A (nsplit=16): Opart 4,194,304 fp32 (16 MB) + M/L 65,536 each
  float* Opart = R;
  float* Mpart = R + 4194304LL;
  float* Lpart = R + 4194304LL + 65536;
  // phase B: chain arrays (each 1,048,576 ushorts)
  ushort* cb = (ushort*)R;
  ushort* zah = cb;                ushort* zal = cb + 1048576LL;
  ushort* zaTh = cb + 2097152LL;
  ushort* zbh = cb + 4194304LL;
  ushort* zbTh = cb + 6291456LL;
  ushort* Ph = cb + 8388608LL;     ushort* Pl = cb + 9437184LL;
  ushort* PTh = cb + 10485760LL;   ushort* PTl = cb + 11534336LL;
  ushort* P2h = cb + 12582912LL;   ushort* P2l = cb + 13631488LL;
  ushort* P2Th = cb + 14680064LL;  ushort* P2Tl = cb + 15728640LL;
  ushort* T2Th = cb + 18874368LL;  ushort* T2Tl = cb + 19922944LL;
  // Y recurrence buffers (hi-only iters): live in lo-regions unused before split
  ushort* Yah = Pl;    ushort* YaTh = PTl;
  ushort* Ybh = P2l;   ushort* YbTh = P2Tl;
  // phase C: fused attn output (b*n,512) + conv buffer
  ushort* ao2_bf = (ushort*)R;                  // 8388608 ushorts
  ushort* cv_bf  = (ushort*)R + 8388608LL;      // 8388608 ushorts

  // fused-qkv addressing constants for flash
  const long long QKV_S = 12582912LL;  // batch stride (8192*1536)
  const long long QKV_H = 64LL;        // head stride
  const int QKV_R = 1536;              // row stride
  const long long CPT_S = 131072LL;    // compact [bh][256][64]: (bh>>3) stride
  const long long CPT_H = 16384LL;     // (bh&7) stride
  const int CPT_R = 64;

  // 0. weight transposes + bf16 convert
  hipLaunchKernelGGL(convert_T_bf16, dim3(3072), dim3(256), 0, stream,
                     w_qkv, wqT_bf, 512, 1536);
  hipLaunchKernelGGL(convert_T_bf16, dim3(1024), dim3(256), 0, stream,
                     w_out, woT_bf, 512, 512);
  // 1. LayerNorm -> bf16
  hipLaunchKernelGGL(ln_kernel, dim3(16384), dim3(256), 0, stream, x, ln_w, ln_b, xn_bf);
  // 2. qkv GEMM (MFMA), fused (b*n,1536) output, q-part x0.125
  hipLaunchKernelGGL(gemm_bf16, dim3(12, 128), dim3(256), 0, stream,
                     xn_bf, wqT_bf, nullptr, qkv_bf, nullptr, nullptr, 512, 2);
  // 3. landmarks
  hipLaunchKernelGGL(landmark_kernel, dim3(256, 16), dim3(64), 0, stream,
                     qkv_bf, qlf, klTf, ql_bf, kl_bf);
  // 4. sim2 = ql @ klT -> a2 (fp32) ; softmax
  {
    dim3 g(4, 4, 16);
    hipLaunchKernelGGL(gemm_f32, g, dim3(256), 0, stream, qlf, klTf, a2,
                       64, 64, 256, 256, 16384LL, 16384LL, 65536LL);
  }
  hipLaunchKernelGGL(softmax256, dim3(1024), dim3(256), 0, stream, a2);
  // 5. a3v = softmax(ql @ k^T) @ v  -- MFMA flash, nsplit=16 (4 blocks/CU), merge
  hipLaunchKernelGGL(flash_mfma, dim3(16, 4, 16), dim3(256), 0, stream,
                     ql_bf, qkv_bf + 512, qkv_bf + 1024, (float*)nullptr,
                     (const ushort*)nullptr, Opart, Mpart, Lpart,
                     CPT_S, CPT_H, CPT_R,
                     QKV_S, QKV_H, QKV_R,
                     QKV_S, QKV_H, QKV_R,
                     0LL, 8, 16);
  hipLaunchKernelGGL(flash_merge, dim3(1024), dim3(256), 0, stream,
                     Opart, Mpart, Lpart, a3vTh, a3vTl, 16);
  // 6. pinv of a2 via Newton-Schulz; Y-recurrence saves the per-iter a2@z launch
  hipLaunchKernelGGL(pm_init, dim3(1), dim3(64), 0, stream, pm);
  hipLaunchKernelGGL(a2_sums, dim3(8, 16), dim3(256), 0, stream, a2, pm);
  hipLaunchKernelGGL(pinv_init, dim3(16, 16), dim3(256), 0, stream, a2, pm,
                     a2h, a2l, zah, zaTh);
  // Y0 = a2 @ z0
  launch_split(stream, 8, a2h, nullptr, zaTh, nullptr, 65536,
               nullptr, nullptr, 0.f, nullptr, nullptr, 0.f,
               Yah, nullptr, YaTh, nullptr, 65536, 256, 1.f);
  {
    ushort *zh = zah, *zTh = zaTh, *zwh = zbh, *zwTh = zbTh;
    ushort *Yh = Yah, *YTh = YaTh, *Ywh = Ybh, *YwTh = YbTh;
    for (int it = 0; it < 5; ++it) {
      // P2 = Y^2
      launch_split(stream, 8, Yh, nullptr, YTh, nullptr, 65536,
                   nullptr, nullptr, 0.f, nullptr, nullptr, 0.f,
                   P2h, nullptr, P2Th, nullptr, 65536, 256, 1.f);
      // T2 = Y@P2 + 15Y - 7P2 (transposed out)
      launch_split(stream, 8, Yh, nullptr, P2Th, nullptr, 65536,
                   Yh, nullptr, 15.f, P2h, nullptr, -7.f,
                   nullptr, nullptr, T2Th, nullptr, 65536, 256, 1.f);
      if (it < 4) {  // dual update: z' and Y' in one launch
        hipLaunchKernelGGL(gemm_dual, dim3(8, 8, 16), dim3(256), 0, stream,
                           zh, Yh, T2Th, zwh, zwTh, Ywh, YwTh);
        ushort* t;
        t = zh; zh = zwh; zwh = t;  t = zTh; zTh = zwTh; zwTh = t;
        t = Yh; Yh = Ywh; Ywh = t;  t = YTh; YTh = YwTh; YwTh = t;
      } else {       // last hi iter: z-only update (Y no longer needed)
        launch_split(stream, 8, zh, nullptr, T2Th, nullptr, 65536,
                     zh, nullptr, 3.25f, nullptr, nullptr, 0.f,
                     zwh, nullptr, zwTh, nullptr, 65536, 256, -0.25f);
      }
    }
  }
  // final iteration: full split precision, fresh P = a2@z5 (z5 = zbh/zbTh)
  launch_split(stream, 8, a2h, a2l, zbTh, nullptr, 65536,
               nullptr, nullptr, 0.f, nullptr, nullptr, 0.f,
               Ph, Pl, PTh, PTl, 65536, 256, 1.f);
  launch_split(stream, 8, Ph, Pl, PTh, PTl, 65536,
               nullptr, nullptr, 0.f, nullptr, nullptr, 0.f,
               P2h, P2l, P2Th, P2Tl, 65536, 256, 1.f);
  launch_split(stream, 8, Ph, Pl, P2Th, P2Tl, 65536,
               Ph, Pl, 15.f, P2h, P2l, -7.f,
               nullptr, nullptr, T2Th, T2Tl, 65536, 256, 1.f);
  launch_split(stream, 8, zbh, nullptr, T2Th, T2Tl, 65536,
               zbh, nullptr, 3.25f, nullptr, nullptr, 0.f,
               zah, zal, nullptr, nullptr, 65536, 256, -0.25f);
  // 7. tb = z6 @ a3v  (split; hi-only bf16 output)
  launch_split(stream, 2, zah, zal, a3vTh, a3vTl, 16384,
               nullptr, nullptr, 0.f, nullptr, nullptr, 0.f,
               tb_bf, nullptr, nullptr, nullptr, 16384, 64, 1.f);
  // 8. depthwise conv residual -> cv (bf16); overwrites dead P-region of chain
  hipLaunchKernelGGL(conv_store, dim3(64, 16), dim3(256), 0, stream,
                     qkv_bf, conv_w, cv_bf);
  // 9. out1 = softmax(q @ kl^T) @ tb  -- MFMA flash, fused +cv, (b*n,512) bf16 out
  hipLaunchKernelGGL(flash_mfma, dim3(1, 128, 16), dim3(256), 0, stream,
                     qkv_bf, kl_bf, tb_bf, (float*)ao2_bf, cv_bf,
                     (float*)nullptr, (float*)nullptr, (float*)nullptr,
                     QKV_S, QKV_H, QKV_R,
                     CPT_S, CPT_H, CPT_R,
                     CPT_S, CPT_H, CPT_R,
                     0LL, 4, 1);
  // 10. final: out = ao2 @ w_out + b_out + x (MFMA)
  hipLaunchKernelGGL(gemm_bf16, dim3(4, 128), dim3(256), 0, stream,
                     ao2_bf, woT_bf, out, nullptr, b_out, x, 512, 3);
}

// Round 8
// 606.131 us; speedup vs baseline: 1.0180x; 1.0180x over previous
//
#include <hip/hip_runtime.h>

// Problem constants: b=2, n=8192, DIM=512, HEADS=8, DIM_HEAD=64, M_LAND=256,
// l=32 landmark groups, KS=33. pad==0 and mask all-true -> masking dead code.

typedef __attribute__((ext_vector_type(8))) short bf16x8;
typedef __attribute__((ext_vector_type(4))) float f32x4;

static __device__ __forceinline__ ushort f2bf(float f) {
  union { float f; unsigned u; } c; c.f = f;
  const unsigned r = c.u + 0x7fffu + ((c.u >> 16) & 1u);
  return (ushort)(r >> 16);
}
static __device__ __forceinline__ float bf2f(ushort u) {
  union { unsigned u; float f; } c; c.u = ((unsigned)u) << 16;
  return c.f;
}

// async global->LDS, 16B per lane. LDS dest is wave-uniform base + lane*16.
typedef __attribute__((address_space(1))) const unsigned int guint;
typedef __attribute__((address_space(3))) unsigned int luint;
static __device__ __forceinline__ void gload_lds16(const void* g, void* l) {
  __builtin_amdgcn_global_load_lds((guint*)g, (luint*)l, 16, 0, 0);
}

// ---------------- LayerNorm: one block per row of 512, bf16 output ----------------
__global__ __launch_bounds__(256) void ln_kernel(const float* __restrict__ x,
                                                 const float* __restrict__ w,
                                                 const float* __restrict__ b,
                                                 ushort* __restrict__ xn) {
  const int row = blockIdx.x;
  const int t = threadIdx.x;
  const float* xr = x + (long long)row * 512;
  float v0 = xr[t], v1 = xr[t + 256];
  __shared__ float red[8];
  float s = v0 + v1;
#pragma unroll
  for (int o = 32; o; o >>= 1) s += __shfl_xor(s, o);
  if ((t & 63) == 0) red[t >> 6] = s;
  __syncthreads();
  const float mu = (red[0] + red[1] + red[2] + red[3]) * (1.0f / 512.0f);
  const float d0 = v0 - mu, d1 = v1 - mu;
  float qs = d0 * d0 + d1 * d1;
#pragma unroll
  for (int o = 32; o; o >>= 1) qs += __shfl_xor(qs, o);
  if ((t & 63) == 0) red[4 + (t >> 6)] = qs;
  __syncthreads();
  const float var = (red[4] + red[5] + red[6] + red[7]) * (1.0f / 512.0f);
  const float rs = rsqrtf(var + 1e-5f);
  ushort* xo = xn + (long long)row * 512;
  xo[t] = f2bf(d0 * rs * w[t] + b[t]);
  xo[t + 256] = f2bf(d1 * rs * w[t + 256] + b[t + 256]);
}

// ------------- transpose + convert fp32 [R][Cc] -> bf16 [Cc][R] -------------
__global__ __launch_bounds__(256) void convert_T_bf16(const float* __restrict__ in,
                                                      ushort* __restrict__ out,
                                                      int R, int Cc) {
  const long long i = (long long)blockIdx.x * 256 + threadIdx.x;
  if (i >= (long long)R * Cc) return;
  const int c = (int)(i / R), r = (int)(i % R);
  out[i] = f2bf(in[(long long)r * Cc + c]);
}

// ---------------- bf16 MFMA GEMM: C = A @ Bt^T  (m97 structure) ----------------
// global_load_lds width-16 staging into linear LDS [128][32], 2 barriers/K-step.
// XCD-bijective block swizzle (requires nwg % 8 == 0; holds: 1536 and 512).
// mode 2: qkv scatter -> uq (x0.125), uk, uv bf16 (b,h,n,d). Each wave's
//   64-col span is one head: part/hh/dst/scale wave-uniform, bb block-uniform,
//   so the "scatter" is a single hoisted base + row*64 + col (1 add/element).
// mode 3: C[r*512+c] = acc + bias[c] + xres[r*512+c]  (fp32)
__global__ __launch_bounds__(256) void gemm_bf16(
    const ushort* __restrict__ A, const ushort* __restrict__ Bt,
    float* __restrict__ C, ushort* __restrict__ uq, ushort* __restrict__ uk,
    ushort* __restrict__ uv,
    const float* __restrict__ bias, const float* __restrict__ xres,
    int K, int mode) {
  const int tid = threadIdx.x;
  const int wave = tid >> 6, lane = tid & 63;
  const int quad = lane >> 4, l16 = lane & 15;

  // XCD swizzle: consecutive work-ids (sharing an A-panel) land on ONE XCD's L2.
  const int gx = gridDim.x;
  const int nwg = gx * gridDim.y;
  const int hid = blockIdx.y * gx + blockIdx.x;
  const int wid = (hid & 7) * (nwg >> 3) + (hid >> 3);
  const int tm = (wid / gx) * 128, tn = (wid % gx) * 128;

  const int wr = (wave >> 1) * 64, wc = (wave & 1) * 64;
  __shared__ __align__(16) ushort As[128 * 32];
  __shared__ __align__(16) ushort Bs[128 * 32];

  f32x4 acc[4][4];
#pragma unroll
  for (int i = 0; i < 4; ++i)
#pragma unroll
    for (int j = 0; j < 4; ++j) acc[i][j] = (f32x4)0.f;

  // staging: chunk i = call*256 + tid; row = i>>2; col-chunk = (i&3)*8 ushorts
  const int r0 = tid >> 2;
  const int c0 = (tid & 3) * 8;
  const ushort* gA0 = A + (long long)(tm + r0) * K + c0;
  const ushort* gA1 = A + (long long)(tm + 64 + r0) * K + c0;
  const ushort* gB0 = Bt + (long long)(tn + r0) * K + c0;
  const ushort* gB1 = Bt + (long long)(tn + 64 + r0) * K + c0;
  ushort* lA0 = As + (wave * 64) * 8;          // wave-uniform LDS bases
  ushort* lA1 = As + (256 + wave * 64) * 8;
  ushort* lB0 = Bs + (wave * 64) * 8;
  ushort* lB1 = Bs + (256 + wave * 64) * 8;

  for (int kb = 0; kb < K; kb += 32) {
    __syncthreads();
    gload_lds16(gA0 + kb, lA0);
    gload_lds16(gA1 + kb, lA1);
    gload_lds16(gB0 + kb, lB0);
    gload_lds16(gB1 + kb, lB1);
    __syncthreads();
    bf16x8 af[4], bfr[4];
#pragma unroll
    for (int t = 0; t < 4; ++t) {
      af[t] = *(const bf16x8*)&As[(wr + t * 16 + l16) * 32 + quad * 8];
      bfr[t] = *(const bf16x8*)&Bs[(wc + t * 16 + l16) * 32 + quad * 8];
    }
#pragma unroll
    for (int i = 0; i < 4; ++i)
#pragma unroll
      for (int j = 0; j < 4; ++j)
        acc[i][j] = __builtin_amdgcn_mfma_f32_16x16x32_bf16(af[i], bfr[j], acc[i][j], 0, 0, 0);
  }

  if (mode == 2) {
    // hoisted scatter: wave-uniform head, block-uniform batch
    const int gcol = tn + wc;                        // 64-aligned
    const int part = gcol >> 9, hh = (gcol >> 6) & 7;
    const float scale = (part == 0) ? 0.125f : 1.0f; // q * DIM_HEAD^-0.5
    ushort* dst = (part == 0) ? uq : ((part == 1) ? uk : uv);
    ushort* base = dst + ((((long long)((tm >> 13) * 8 + hh)) << 13) +
                          (tm & 8191) + wr + quad * 4) * 64 + l16;
#pragma unroll
    for (int ti = 0; ti < 4; ++ti) {
#pragma unroll
      for (int r = 0; r < 4; ++r) {
        ushort* drow = base + (ti * 16 + r) * 64;
#pragma unroll
        for (int tj = 0; tj < 4; ++tj)
          drow[tj * 16] = f2bf(acc[ti][tj][r] * scale);
      }
    }
  } else {  // mode 3
#pragma unroll
    for (int ti = 0; ti < 4; ++ti) {
#pragma unroll
      for (int r = 0; r < 4; ++r) {
        const long long gr = tm + wr + ti * 16 + quad * 4 + r;
#pragma unroll
        for (int tj = 0; tj < 4; ++tj) {
          const int gc = tn + wc + tj * 16 + l16;
          const long long idx = gr * 512 + gc;
          C[idx] = acc[ti][tj][r] + bias[gc] + xres[idx];
        }
      }
    }
  }
}

// ---------------- fp32 GEMM (sim2 only): C = A@B ----------------
__global__ __launch_bounds__(256) void gemm_f32(
    const float* __restrict__ A, const float* __restrict__ B,
    float* __restrict__ C, int K, int lda, int ldb, int ldc,
    long long sA, long long sB, long long sC) {
  const int tid = threadIdx.x;
  const int batch = blockIdx.z;
  A += (long long)batch * sA;
  B += (long long)batch * sB;
  C += (long long)batch * sC;
  const int tm = blockIdx.y * 64;
  const int tn = blockIdx.x * 64;

  __shared__ float As[16][65];
  __shared__ float Bs[16][65];

  const int tx = tid & 15, ty = tid >> 4;
  const int ar = tid >> 2, ac = (tid & 3) * 4;
  const int br = tid >> 4, bc = (tid & 15) * 4;

  float acc[4][4];
#pragma unroll
  for (int i = 0; i < 4; ++i)
#pragma unroll
    for (int j = 0; j < 4; ++j) acc[i][j] = 0.f;

  for (int kb = 0; kb < K; kb += 16) {
    const float4 a4 = *(const float4*)(A + (long long)(tm + ar) * lda + kb + ac);
    const float4 b4 = *(const float4*)(B + (long long)(kb + br) * ldb + tn + bc);
    __syncthreads();
    As[ac + 0][ar] = a4.x; As[ac + 1][ar] = a4.y;
    As[ac + 2][ar] = a4.z; As[ac + 3][ar] = a4.w;
    Bs[br][bc + 0] = b4.x; Bs[br][bc + 1] = b4.y;
    Bs[br][bc + 2] = b4.z; Bs[br][bc + 3] = b4.w;
    __syncthreads();
#pragma unroll
    for (int kk = 0; kk < 16; ++kk) {
      float av[4], bv[4];
#pragma unroll
      for (int i = 0; i < 4; ++i) av[i] = As[kk][ty * 4 + i];
#pragma unroll
      for (int j = 0; j < 4; ++j) bv[j] = Bs[kk][tx * 4 + j];
#pragma unroll
      for (int i = 0; i < 4; ++i)
#pragma unroll
        for (int j = 0; j < 4; ++j) acc[i][j] = fmaf(av[i], bv[j], acc[i][j]);
    }
  }
#pragma unroll
  for (int i = 0; i < 4; ++i) {
    const long long r = tm + ty * 4 + i;
#pragma unroll
    for (int j = 0; j < 4; ++j) C[r * ldc + tn + tx * 4 + j] = acc[i][j];
  }
}

// -------- split/hi bf16 MFMA batched GEMM stage body for the pinv chain --------
static __device__ __forceinline__ void stage_body(
    int tc, int tr, int bh,
    const ushort* __restrict__ Ah, const ushort* __restrict__ Al,
    const ushort* __restrict__ BTh, const ushort* __restrict__ BTl,
    const ushort* __restrict__ D1h, const ushort* __restrict__ D1l,
    const ushort* __restrict__ D2h, const ushort* __restrict__ D2l,
    ushort* __restrict__ Ch, ushort* __restrict__ Cl,
    ushort* __restrict__ CTh, ushort* __restrict__ CTl,
    float alpha, float beta1, float beta2,
    long long sBT, long long sC, int ldc,
    ushort (*TBh)[36], ushort (*TBl)[36]) {
  const int tid = threadIdx.x;
  const int wave = tid >> 6, lane = tid & 63;
  const int quad = lane >> 4, l16 = lane & 15;
  const bool hasAl = (Al != nullptr);
  const bool hasBl = (BTl != nullptr);

  const ushort* A_h = Ah + (long long)bh * 65536 + (long long)(tr + wave * 16 + l16) * 256;
  const ushort* A_l = (hasAl ? Al : Ah) + (long long)bh * 65536 +
                      (long long)(tr + wave * 16 + l16) * 256;
  const ushort* B_h0 = BTh + (long long)bh * sBT + (long long)(tc + l16) * 256;
  const ushort* B_l0 = (hasBl ? BTl : BTh) + (long long)bh * sBT +
                       (long long)(tc + l16) * 256;

  f32x4 acc[2];
  acc[0] = (f32x4)0.f; acc[1] = (f32x4)0.f;

#pragma unroll
  for (int kc = 0; kc < 8; ++kc) {
    const int ko = kc * 32 + quad * 8;
    const bf16x8 a_h = *(const bf16x8*)(A_h + ko);
    bf16x8 a_l;
    if (hasAl) a_l = *(const bf16x8*)(A_l + ko);
#pragma unroll
    for (int ct = 0; ct < 2; ++ct) {
      const bf16x8 b_h = *(const bf16x8*)(B_h0 + ct * 4096 + ko);
      acc[ct] = __builtin_amdgcn_mfma_f32_16x16x32_bf16(a_h, b_h, acc[ct], 0, 0, 0);
      if (hasBl) {
        const bf16x8 b_l = *(const bf16x8*)(B_l0 + ct * 4096 + ko);
        acc[ct] = __builtin_amdgcn_mfma_f32_16x16x32_bf16(a_h, b_l, acc[ct], 0, 0, 0);
      }
      if (hasAl)
        acc[ct] = __builtin_amdgcn_mfma_f32_16x16x32_bf16(a_l, b_h, acc[ct], 0, 0, 0);
    }
  }

#pragma unroll
  for (int ct = 0; ct < 2; ++ct) {
#pragma unroll
    for (int r = 0; r < 4; ++r) {
      const int rl = wave * 16 + quad * 4 + r;
      const int clc = ct * 16 + l16;
      float val = alpha * acc[ct][r];
      if (D1h) {
        const long long di = (long long)bh * 65536 + (long long)(tr + rl) * 256 + tc + clc;
        float d = bf2f(D1h[di]);
        if (D1l) d += bf2f(D1l[di]);
        val += beta1 * d;
      }
      if (D2h) {
        const long long di = (long long)bh * 65536 + (long long)(tr + rl) * 256 + tc + clc;
        float d = bf2f(D2h[di]);
        if (D2l) d += bf2f(D2l[di]);
        val += beta2 * d;
      }
      const ushort h = f2bf(val);
      TBh[rl][clc] = h;
      TBl[rl][clc] = f2bf(val - bf2f(h));
    }
  }
  __syncthreads();
  if (Ch) {  // row-major store, coalesced uint4
    const int rl = tid >> 2, seg = (tid & 3) * 8;
    const long long ci = (long long)bh * sC + (long long)(tr + rl) * ldc + tc + seg;
    *(uint4*)&Ch[ci] = *(const uint4*)&TBh[rl][seg];
    if (Cl) *(uint4*)&Cl[ci] = *(const uint4*)&TBl[rl][seg];
  }
  if (CTh) {  // transposed store: gather 8 from LDS, uint4 out
    const int clc = tid >> 3, seg = (tid & 7) * 8;
    union { uint4 u; ushort s[8]; } th, tl;
#pragma unroll
    for (int j = 0; j < 8; ++j) {
      th.s[j] = TBh[seg + j][clc];
      tl.s[j] = TBl[seg + j][clc];
    }
    const long long gi = (long long)bh * 65536 + (long long)(tc + clc) * 256 + tr + seg;
    *(uint4*)&CTh[gi] = th.u;
    if (CTl) *(uint4*)&CTl[gi] = tl.u;
  }
}

// standard stage kernel: grid (cols/32, rows/64, 16)
__global__ __launch_bounds__(256) void gemm_split(
    const ushort* __restrict__ Ah, const ushort* __restrict__ Al,
    const ushort* __restrict__ BTh, const ushort* __restrict__ BTl,
    const ushort* __restrict__ D1h, const ushort* __restrict__ D1l,
    const ushort* __restrict__ D2h, const ushort* __restrict__ D2l,
    ushort* __restrict__ Ch, ushort* __restrict__ Cl,
    ushort* __restrict__ CTh, ushort* __restrict__ CTl,
    float alpha, float beta1, float beta2,
    long long sBT, long long sC, int ldc) {
  __shared__ ushort TBh[64][36];
  __shared__ ushort TBl[64][36];
  stage_body(blockIdx.x * 32, blockIdx.y * 64, blockIdx.z,
             Ah, Al, BTh, BTl, D1h, D1l, D2h, D2l, Ch, Cl, CTh, CTl,
             alpha, beta1, beta2, sBT, sC, ldc, TBh, TBl);
}

// dual-update kernel: one launch computes BOTH  z' = -0.25 z@T2 + 3.25 z  and
// Y' = -0.25 Y@T2 + 3.25 Y. grid (8, 8, 16): y<4 -> z rows, y>=4 -> Y rows.
__global__ __launch_bounds__(256) void gemm_dual(
    const ushort* __restrict__ zA, const ushort* __restrict__ yA,
    const ushort* __restrict__ BT,
    ushort* __restrict__ zC, ushort* __restrict__ zCT,
    ushort* __restrict__ yC, ushort* __restrict__ yCT) {
  __shared__ ushort TBh[64][36];
  __shared__ ushort TBl[64][36];
  const int by = blockIdx.y;
  if (by < 4)
    stage_body(blockIdx.x * 32, by * 64, blockIdx.z,
               zA, nullptr, BT, nullptr, zA, nullptr, nullptr, nullptr,
               zC, nullptr, zCT, nullptr, -0.25f, 3.25f, 0.f,
               65536, 65536, 256, TBh, TBl);
  else
    stage_body(blockIdx.x * 32, (by - 4) * 64, blockIdx.z,
               yA, nullptr, BT, nullptr, yA, nullptr, nullptr, nullptr,
               yC, nullptr, yCT, nullptr, -0.25f, 3.25f, 0.f,
               65536, 65536, 256, TBh, TBl);
}

// ------------- landmark means from bf16 q,k -------------
__global__ __launch_bounds__(64) void landmark_kernel(
    const ushort* __restrict__ q, const ushort* __restrict__ k,
    float* __restrict__ qlf, float* __restrict__ klTf,
    ushort* __restrict__ qlb, ushort* __restrict__ klb) {
  const int bh = blockIdx.y, i = blockIdx.x, d = threadIdx.x;
  const long long base = (((long long)bh << 13) + i * 32) * 64 + d;
  float sq = 0.f, sk = 0.f;
#pragma unroll
  for (int j = 0; j < 32; ++j) {
    sq += bf2f(q[base + j * 64]);
    sk += bf2f(k[base + j * 64]);
  }
  const float mq = sq * (1.0f / 32.0f), mk = sk * (1.0f / 32.0f);
  qlf[((long long)bh * 256 + i) * 64 + d] = mq;
  klTf[((long long)bh * 64 + d) * 256 + i] = mk;
  qlb[((long long)bh * 256 + i) * 64 + d] = f2bf(mq);
  klb[((long long)bh * 256 + i) * 64 + d] = f2bf(mk);
}

// ---------------- softmax over rows of length 256: wave per row ----------------
__global__ __launch_bounds__(256) void softmax256(float* __restrict__ a) {
  const long long row = (long long)blockIdx.x * 4 + (threadIdx.x >> 6);
  const int lane = threadIdx.x & 63;
  float* p = a + row * 256 + lane * 4;
  float4 vv = *(float4*)p;
  float m = fmaxf(fmaxf(vv.x, vv.y), fmaxf(vv.z, vv.w));
#pragma unroll
  for (int o = 32; o; o >>= 1) m = fmaxf(m, __shfl_xor(m, o));
  vv.x = __expf(vv.x - m); vv.y = __expf(vv.y - m);
  vv.z = __expf(vv.z - m); vv.w = __expf(vv.w - m);
  float s = vv.x + vv.y + vv.z + vv.w;
#pragma unroll
  for (int o = 32; o; o >>= 1) s += __shfl_xor(s, o);
  const float inv = 1.0f / s;
  vv.x *= inv; vv.y *= inv; vv.z *= inv; vv.w *= inv;
  *(float4*)p = vv;
}

// ---------------- bf16 MFMA flash attention: Out = softmax(Q K^T) V ----------------
// nsplit==1 && CV==null: writes bf16 to Out (ushort*), sO in elements.
// nsplit==1 && CV!=null: fused epilogue -- adds conv residual CV (b,h,n,d) and
//   writes directly into (b*n, 512) layout at Out (ushort*), col block h*64.
__global__ __launch_bounds__(256) void flash_mfma(
    const ushort* __restrict__ Q, const ushort* __restrict__ K,
    const ushort* __restrict__ V, float* __restrict__ Out,
    const ushort* __restrict__ CV,
    float* __restrict__ Opart, float* __restrict__ Mpart,
    float* __restrict__ Lpart,
    long long sQ, long long sK, long long sV, long long sO,
    int iters, int nsplit) {
  const int bh = blockIdx.z, mt = blockIdx.y, ns = blockIdx.x;
  const int tid = threadIdx.x;
  const int wave = tid >> 6, lane = tid & 63;
  const int quad = lane >> 4, l16 = lane & 15;
  __shared__ ushort Vt[64][72];  // [d][key]
  __shared__ ushort Ps[64][72];  // [q-row][key]

  const ushort* Qb = Q + (long long)bh * sQ + (long long)(mt * 64) * 64;
  const ushort* Kb = K + (long long)bh * sK + (long long)(ns * iters * 64) * 64;
  const ushort* Vb = V + (long long)bh * sV + (long long)(ns * iters * 64) * 64;

  bf16x8 aq[2];
#pragma unroll
  for (int kc = 0; kc < 2; ++kc)
    aq[kc] = *(const bf16x8*)(Qb + (long long)(wave * 16 + l16) * 64 + kc * 32 + quad * 8);

  f32x4 acc[4];
  float mrow[4], lrow[4];
#pragma unroll
  for (int dt = 0; dt < 4; ++dt) acc[dt] = (f32x4)0.f;
#pragma unroll
  for (int r = 0; r < 4; ++r) { mrow[r] = -1e30f; lrow[r] = 0.f; }

  for (int it = 0; it < iters; ++it) {
    __syncthreads();
    for (int i = tid; i < 512; i += 256) {
      const int key = i & 63, c8 = (i >> 6) * 8;
      union { uint4 u; ushort s[8]; } t;
      t.u = *(const uint4*)(Vb + (long long)(it * 64 + key) * 64 + c8);
#pragma unroll
      for (int j = 0; j < 8; ++j) Vt[c8 + j][key] = t.s[j];
    }
    f32x4 sfr[4];
#pragma unroll
    for (int kt = 0; kt < 4; ++kt) {
      sfr[kt] = (f32x4)0.f;
#pragma unroll
      for (int kc = 0; kc < 2; ++kc) {
        const bf16x8 bk = *(const bf16x8*)(Kb +
            (long long)(it * 64 + kt * 16 + l16) * 64 + kc * 32 + quad * 8);
        sfr[kt] = __builtin_amdgcn_mfma_f32_16x16x32_bf16(aq[kc], bk, sfr[kt], 0, 0, 0);
      }
    }
#pragma unroll
    for (int r = 0; r < 4; ++r) {
      float rm = fmaxf(fmaxf(sfr[0][r], sfr[1][r]), fmaxf(sfr[2][r], sfr[3][r]));
#pragma unroll
      for (int off = 1; off < 16; off <<= 1) rm = fmaxf(rm, __shfl_xor(rm, off));
      const float mn = fmaxf(mrow[r], rm);
      const float scv = __expf(mrow[r] - mn);
      float rs = 0.f;
#pragma unroll
      for (int kt = 0; kt < 4; ++kt) {
        const float p = __expf(sfr[kt][r] - mn);
        sfr[kt][r] = p;
        rs += p;
      }
#pragma unroll
      for (int off = 1; off < 16; off <<= 1) rs += __shfl_xor(rs, off);
      lrow[r] = lrow[r] * scv + rs;
      mrow[r] = mn;
#pragma unroll
      for (int dt = 0; dt < 4; ++dt) acc[dt][r] *= scv;
#pragma unroll
      for (int kt = 0; kt < 4; ++kt)
        Ps[wave * 16 + quad * 4 + r][kt * 16 + l16] = f2bf(sfr[kt][r]);
    }
    __syncthreads();
#pragma unroll
    for (int kc = 0; kc < 2; ++kc) {
      const bf16x8 ap = *(const bf16x8*)&Ps[wave * 16 + l16][kc * 32 + quad * 8];
#pragma unroll
      for (int dt = 0; dt < 4; ++dt) {
        const bf16x8 bv = *(const bf16x8*)&Vt[dt * 16 + l16][kc * 32 + quad * 8];
        acc[dt] = __builtin_amdgcn_mfma_f32_16x16x32_bf16(ap, bv, acc[dt], 0, 0, 0);
      }
    }
  }

  if (nsplit == 1) {
    if (CV) {  // fused: add conv residual, write (b*n, 512) layout
      const int b = bh >> 3, h = bh & 7;
      const ushort* cvb = CV + (((long long)bh << 13) + mt * 64) * 64;
      ushort* Ob = (ushort*)Out + ((long long)(b * 8192 + mt * 64)) * 512 + h * 64;
#pragma unroll
      for (int r = 0; r < 4; ++r) {
        const float inv = 1.0f / lrow[r];
        const int row = wave * 16 + quad * 4 + r;
#pragma unroll
        for (int dt = 0; dt < 4; ++dt) {
          const int col = dt * 16 + l16;
          const float val = acc[dt][r] * inv + bf2f(cvb[(long long)row * 64 + col]);
          Ob[(long long)row * 512 + col] = f2bf(val);
        }
      }
    } else {
      ushort* Ob = (ushort*)Out + (long long)bh * sO + (long long)(mt * 64) * 64;
#pragma unroll
      for (int r = 0; r < 4; ++r) {
        const float inv = 1.0f / lrow[r];
        const int row = wave * 16 + quad * 4 + r;
#pragma unroll
        for (int dt = 0; dt < 4; ++dt)
          Ob[(long long)row * 64 + dt * 16 + l16] = f2bf(acc[dt][r] * inv);
      }
    }
  } else {
    const long long pbase = ((long long)(bh * gridDim.y + mt) * nsplit + ns);
    const int row0 = wave * 16 + quad * 4;
#pragma unroll
    for (int r = 0; r < 4; ++r) {
#pragma unroll
      for (int dt = 0; dt < 4; ++dt)
        Opart[(pbase * 64 + row0 + r) * 64 + dt * 16 + l16] = acc[dt][r];
      if (l16 == 0) {
        Mpart[pbase * 64 + row0 + r] = mrow[r];
        Lpart[pbase * 64 + row0 + r] = lrow[r];
      }
    }
  }
}

// ------- merge flash partials -> a3v^T hi/lo bf16 [bh][64][256]; 1024 blocks -------
__global__ __launch_bounds__(256) void flash_merge(
    const float* __restrict__ Opart, const float* __restrict__ Mpart,
    const float* __restrict__ Lpart, ushort* __restrict__ a3vTh,
    ushort* __restrict__ a3vTl, int nsplit) {
  const int bm = blockIdx.x >> 4;  // bh*4 + mt
  const int rg = blockIdx.x & 15;  // 4-row group
  const int bh = bm >> 2, mt = bm & 3;
  const int c = threadIdx.x & 63, rb = threadIdx.x >> 6;
  const int r = rg * 4 + rb;
  float ms = -1e30f;
  for (int ns = 0; ns < nsplit; ++ns)
    ms = fmaxf(ms, Mpart[(bm * nsplit + ns) * 64 + r]);
  float L = 0.f, O = 0.f;
  for (int ns = 0; ns < nsplit; ++ns) {
    const float w = __expf(Mpart[(bm * nsplit + ns) * 64 + r] - ms);
    L += w * Lpart[(bm * nsplit + ns) * 64 + r];
    O += w * Opart[((long long)(bm * nsplit + ns) * 64 + r) * 64 + c];
  }
  const float val = O / L;
  const ushort h = f2bf(val);
  const long long ti = (long long)bh * 16384 + (long long)c * 256 + mt * 64 + r;
  a3vTh[ti] = h;
  a3vTl[ti] = f2bf(val - bf2f(h));
}

// ------- pm init + a2 row/col-sum global maxes (atomicMax on positive floats) -------
__global__ void pm_init(float* __restrict__ pm) {
  if (threadIdx.x < 2) pm[threadIdx.x] = 0.f;
}

__global__ __launch_bounds__(256) void a2_sums(const float* __restrict__ a2,
                                               float* __restrict__ pm) {
  // grid (8, 16): p = 32-row/col slice, bh
  const int p = blockIdx.x, bh = blockIdx.y;
  const float* m = a2 + (long long)bh * 65536;
  const int tid = threadIdx.x;
  __shared__ float red[4];
  {  // row sums: 8 threads per row, 32 elems each
    const int r = p * 32 + (tid >> 3);
    const int c0 = (tid & 7) * 32;
    float s = 0.f;
#pragma unroll 8
    for (int j = 0; j < 32; ++j) s += m[r * 256 + c0 + j];
    s += __shfl_xor(s, 1); s += __shfl_xor(s, 2); s += __shfl_xor(s, 4);
    float mx = s;
#pragma unroll
    for (int o = 8; o < 64; o <<= 1) mx = fmaxf(mx, __shfl_xor(mx, o));
    if ((tid & 63) == 0) red[tid >> 6] = mx;
    __syncthreads();
    if (tid == 0) {
      mx = fmaxf(fmaxf(red[0], red[1]), fmaxf(red[2], red[3]));
      atomicMax((int*)&pm[0], __float_as_int(mx));
    }
    __syncthreads();
  }
  {  // col sums: 8 threads per col, 32 rows each
    const int c = p * 32 + (tid >> 3);
    const int r0 = (tid & 7) * 32;
    float s = 0.f;
#pragma unroll 8
    for (int j = 0; j < 32; ++j) s += m[(r0 + j) * 256 + c];
    s += __shfl_xor(s, 1); s += __shfl_xor(s, 2); s += __shfl_xor(s, 4);
    float mx = s;
#pragma unroll
    for (int o = 8; o < 64; o <<= 1) mx = fmaxf(mx, __shfl_xor(mx, o));
    if ((tid & 63) == 0) red[tid >> 6] = mx;
    __syncthreads();
    if (tid == 0) {
      mx = fmaxf(fmaxf(red[0], red[1]), fmaxf(red[2], red[3]));
      atomicMax((int*)&pm[1], __float_as_int(mx));
    }
  }
}

// ---- pinv init: split a2 -> hi/lo; z0 = a2^T * s (hi row-major + hi transposed) ----
__global__ __launch_bounds__(256) void pinv_init(
    const float* __restrict__ a2, const float* __restrict__ pm,
    ushort* __restrict__ a2h, ushort* __restrict__ a2l,
    ushort* __restrict__ zh, ushort* __restrict__ zTh) {
  const int bh = blockIdx.y;
  const float s = 1.0f / (pm[0] * pm[1]);
  const long long base = (long long)bh * 65536;
  const int i0 = blockIdx.x * 4096;
  for (int t = threadIdx.x; t < 4096; t += 256) {
    const int idx = i0 + t;
    const float v = a2[base + idx];
    const ushort h = f2bf(v);
    a2h[base + idx] = h;
    a2l[base + idx] = f2bf(v - bf2f(h));
    zTh[base + idx] = f2bf(v * s);  // zT = a2 * s
    const float vt = a2[base + ((long long)(idx & 255) << 8) + (idx >> 8)] * s;
    zh[base + idx] = f2bf(vt);
  }
}

// -------- depthwise conv (KS=33) from bf16 v -> cv (bf16, (b,h,n,d)) --------
__global__ __launch_bounds__(256) void conv_store(const ushort* __restrict__ v,
                                                  const float* __restrict__ w,
                                                  ushort* __restrict__ cv) {
  const int bh = blockIdx.y;
  const int n0 = blockIdx.x * 128;
  const int h = bh & 7;
  __shared__ float vs[160][64];
  __shared__ float ws[33];
  if (threadIdx.x < 33) ws[threadIdx.x] = w[h * 33 + threadIdx.x];
  for (int i = threadIdx.x; i < 160 * 8; i += 256) {
    const int r = i >> 3, c8 = (i & 7) * 8;
    const int n = n0 - 16 + r;
    if (n >= 0 && n < 8192) {
      union { uint4 u; ushort s[8]; } t;
      t.u = *(const uint4*)(v + (((long long)bh << 13) + n) * 64 + c8);
#pragma unroll
      for (int j = 0; j < 8; ++j) vs[r][c8 + j] = bf2f(t.s[j]);
    } else {
#pragma unroll
      for (int j = 0; j < 8; ++j) vs[r][c8 + j] = 0.f;
    }
  }
  __syncthreads();
  const int d = threadIdx.x & 63, r0 = threadIdx.x >> 6;
  for (int rr = r0; rr < 128; rr += 4) {
    float acc = 0.f;
#pragma unroll
    for (int kk = 0; kk < 33; ++kk) acc += ws[kk] * vs[rr + kk][d];
    cv[(((long long)bh << 13) + n0 + rr) * 64 + d] = f2bf(acc);
  }
}

// ---------------- host ----------------
static inline void launch_split(hipStream_t st, int gridX,
    const ushort* Ah, const ushort* Al,
    const ushort* BTh, const ushort* BTl, long long sBT,
    const ushort* D1h, const ushort* D1l, float beta1,
    const ushort* D2h, const ushort* D2l, float beta2,
    ushort* Ch, ushort* Cl, ushort* CTh, ushort* CTl,
    long long sC, int ldc, float alpha) {
  dim3 grid((unsigned)gridX, 4, 16);
  hipLaunchKernelGGL(gemm_split, grid, dim3(256), 0, st, Ah, Al, BTh, BTl,
                     D1h, D1l, D2h, D2l, Ch, Cl, CTh, CTl,
                     alpha, beta1, beta2, sBT, sC, ldc);
}

extern "C" void kernel_launch(void* const* d_in, const int* in_sizes, int n_in,
                              void* d_out, int out_size, void* d_ws, size_t ws_size,
                              hipStream_t stream) {
  const float* x = (const float*)d_in[0];
  // d_in[1] = mask: all-true -> unused
  const float* ln_w = (const float*)d_in[2];
  const float* ln_b = (const float*)d_in[3];
  const float* w_qkv = (const float*)d_in[4];
  const float* w_out = (const float*)d_in[5];
  const float* b_out = (const float*)d_in[6];
  const float* conv_w = (const float*)d_in[7];
  float* out = (float*)d_out;

  float* ws = (float*)d_ws;
  // Region R (10,485,760 floats = 40 MB), time-multiplexed:
  //   phase A: Opart/Mpart/Lpart; phase B: pinv chain; phase C: ao2 + cv (bf16)
  float* R = ws;
  float* a2   = R + 10485760LL;        // 1048576 fp32
  float* qlf  = a2 + 1048576LL;        // 262144
  float* klTf = qlf + 262144LL;        // 262144
  float* pm   = klTf + 262144LL;       // 64
  ushort* q_bf   = (ushort*)(pm + 64); // 8388608 each
  ushort* k_bf   = q_bf + 8388608LL;
  ushort* v_bf   = k_bf + 8388608LL;
  ushort* xn_bf  = v_bf + 8388608LL;
  ushort* ql_bf  = xn_bf + 8388608LL;  // 262144
  ushort* kl_bf  = ql_bf + 262144LL;
  ushort* tb_bf  = kl_bf + 262144LL;   // 262144
  ushort* wqT_bf = tb_bf + 262144LL;   // 786432
  ushort* woT_bf = wqT_bf + 786432LL;  // 262144
  ushort* a2h    = woT_bf + 262144LL;  // 1048576 each
  ushort* a2l    = a2h + 1048576LL;
  ushort* a3vTh  = a2l + 1048576LL;    // 262144 each
  ushort* a3vTl  = a3vTh + 262144LL;

  // phase A (nsplit=16): Opart 4,194,304 fp32 (16 MB) + M/L 65,536 each
  float* Opart = R;
  float* Mpart = R + 4194304LL;
  float* Lpart = R + 4194304LL + 65536;
  // phase B: chain arrays (each 1,048,576 ushorts)
  ushort* cb = (ushort*)R;
  ushort* zah = cb;                ushort* zal = cb + 1048576LL;
  ushort* zaTh = cb + 2097152LL;
  ushort* zbh = cb + 4194304LL;
  ushort* zbTh = cb + 6291456LL;
  ushort* Ph = cb + 8388608LL;     ushort* Pl = cb + 9437184LL;
  ushort* PTh = cb + 10485760LL;   ushort* PTl = cb + 11534336LL;
  ushort* P2h = cb + 12582912LL;   ushort* P2l = cb + 13631488LL;
  ushort* P2Th = cb + 14680064LL;  ushort* P2Tl = cb + 15728640LL;
  ushort* T2Th = cb + 18874368LL;  ushort* T2Tl = cb + 19922944LL;
  // Y recurrence buffers (hi-only iters): live in lo-regions unused before split
  ushort* Yah = Pl;    ushort* YaTh = PTl;
  ushort* Ybh = P2l;   ushort* YbTh = P2Tl;
  // phase C: fused attn output (b*n,512) + conv buffer
  ushort* ao2_bf = (ushort*)R;                  // 8388608 ushorts
  ushort* cv_bf  = (ushort*)R + 8388608LL;      // 8388608 ushorts

  // 0. weight transposes + bf16 convert
  hipLaunchKernelGGL(convert_T_bf16, dim3(3072), dim3(256), 0, stream,
                     w_qkv, wqT_bf, 512, 1536);
  hipLaunchKernelGGL(convert_T_bf16, dim3(1024), dim3(256), 0, stream,
                     w_out, woT_bf, 512, 512);
  // 1. LayerNorm -> bf16
  hipLaunchKernelGGL(ln_kernel, dim3(16384), dim3(256), 0, stream, x, ln_w, ln_b, xn_bf);
  // 2. qkv GEMM (MFMA), scatter q(x0.125),k,v as bf16 (b,h,n,d), hoisted epilogue
  hipLaunchKernelGGL(gemm_bf16, dim3(12, 128), dim3(256), 0, stream,
                     xn_bf, wqT_bf, nullptr, q_bf, k_bf, v_bf, nullptr, nullptr, 512, 2);
  // 3. landmarks
  hipLaunchKernelGGL(landmark_kernel, dim3(256, 16), dim3(64), 0, stream,
                     q_bf, k_bf, qlf, klTf, ql_bf, kl_bf);
  // 4. sim2 = ql @ klT -> a2 (fp32) ; softmax
  {
    dim3 g(4, 4, 16);
    hipLaunchKernelGGL(gemm_f32, g, dim3(256), 0, stream, qlf, klTf, a2,
                       64, 64, 256, 256, 16384LL, 16384LL, 65536LL);
  }
  hipLaunchKernelGGL(softmax256, dim3(1024), dim3(256), 0, stream, a2);
  // 5. a3v = softmax(ql @ k^T) @ v  -- MFMA flash, nsplit=16 (4 blocks/CU), merge
  hipLaunchKernelGGL(flash_mfma, dim3(16, 4, 16), dim3(256), 0, stream,
                     ql_bf, k_bf, v_bf, (float*)nullptr, (const ushort*)nullptr,
                     Opart, Mpart, Lpart,
                     16384LL, 524288LL, 524288LL, 0LL, 8, 16);
  hipLaunchKernelGGL(flash_merge, dim3(1024), dim3(256), 0, stream,
                     Opart, Mpart, Lpart, a3vTh, a3vTl, 16);
  // 6. pinv of a2 via Newton-Schulz; Y-recurrence saves the per-iter a2@z launch
  hipLaunchKernelGGL(pm_init, dim3(1), dim3(64), 0, stream, pm);
  hipLaunchKernelGGL(a2_sums, dim3(8, 16), dim3(256), 0, stream, a2, pm);
  hipLaunchKernelGGL(pinv_init, dim3(16, 16), dim3(256), 0, stream, a2, pm,
                     a2h, a2l, zah, zaTh);
  // Y0 = a2 @ z0
  launch_split(stream, 8, a2h, nullptr, zaTh, nullptr, 65536,
               nullptr, nullptr, 0.f, nullptr, nullptr, 0.f,
               Yah, nullptr, YaTh, nullptr, 65536, 256, 1.f);
  {
    ushort *zh = zah, *zTh = zaTh, *zwh = zbh, *zwTh = zbTh;
    ushort *Yh = Yah, *YTh = YaTh, *Ywh = Ybh, *YwTh = YbTh;
    for (int it = 0; it < 5; ++it) {
      // P2 = Y^2
      launch_split(stream, 8, Yh, nullptr, YTh, nullptr, 65536,
                   nullptr, nullptr, 0.f, nullptr, nullptr, 0.f,
                   P2h, nullptr, P2Th, nullptr, 65536, 256, 1.f);
      // T2 = Y@P2 + 15Y - 7P2 (transposed out)
      launch_split(stream, 8, Yh, nullptr, P2Th, nullptr, 65536,
                   Yh, nullptr, 15.f, P2h, nullptr, -7.f,
                   nullptr, nullptr, T2Th, nullptr, 65536, 256, 1.f);
      if (it < 4) {  // dual update: z' and Y' in one launch
        hipLaunchKernelGGL(gemm_dual, dim3(8, 8, 16), dim3(256), 0, stream,
                           zh, Yh, T2Th, zwh, zwTh, Ywh, YwTh);
        ushort* t;
        t = zh; zh = zwh; zwh = t;  t = zTh; zTh = zwTh; zwTh = t;
        t = Yh; Yh = Ywh; Ywh = t;  t = YTh; YTh = YwTh; YwTh = t;
      } else {       // last hi iter: z-only update (Y no longer needed)
        launch_split(stream, 8, zh, nullptr, T2Th, nullptr, 65536,
                     zh, nullptr, 3.25f, nullptr, nullptr, 0.f,
                     zwh, nullptr, zwTh, nullptr, 65536, 256, -0.25f);
      }
    }
  }
  // final iteration: full split precision, fresh P = a2@z5 (z5 = zbh/zbTh)
  launch_split(stream, 8, a2h, a2l, zbTh, nullptr, 65536,
               nullptr, nullptr, 0.f, nullptr, nullptr, 0.f,
               Ph, Pl, PTh, PTl, 65536, 256, 1.f);
  launch_split(stream, 8, Ph, Pl, PTh, PTl, 65536,
               nullptr, nullptr, 0.f, nullptr, nullptr, 0.f,
               P2h, P2l, P2Th, P2Tl, 65536, 256, 1.f);
  launch_split(stream, 8, Ph, Pl, P2Th, P2Tl, 65536,
               Ph, Pl, 15.f, P2h, P2l, -7.f,
               nullptr, nullptr, T2Th, T2Tl, 65536, 256, 1.f);
  launch_split(stream, 8, zbh, nullptr, T2Th, T2Tl, 65536,
               zbh, nullptr, 3.25f, nullptr, nullptr, 0.f,
               zah, zal, nullptr, nullptr, 65536, 256, -0.25f);
  // 7. tb = z6 @ a3v  (split; hi-only bf16 output)
  launch_split(stream, 2, zah, zal, a3vTh, a3vTl, 16384,
               nullptr, nullptr, 0.f, nullptr, nullptr, 0.f,
               tb_bf, nullptr, nullptr, nullptr, 16384, 64, 1.f);
  // 8. depthwise conv residual -> cv (bf16); overwrites dead P-region of chain
  hipLaunchKernelGGL(conv_store, dim3(64, 16), dim3(256), 0, stream, v_bf, conv_w, cv_bf);
  // 9. out1 = softmax(q @ kl^T) @ tb  -- MFMA flash, fused +cv, (b*n,512) bf16 out
  hipLaunchKernelGGL(flash_mfma, dim3(1, 128, 16), dim3(256), 0, stream,
                     q_bf, kl_bf, tb_bf, (float*)ao2_bf, cv_bf,
                     (float*)nullptr, (float*)nullptr, (float*)nullptr,
                     524288LL, 16384LL, 16384LL, 0LL, 4, 1);
  // 10. final: out = ao2 @ w_out + b_out + x (MFMA)
  hipLaunchKernelGGL(gemm_bf16, dim3(4, 128), dim3(256), 0, stream,
                     ao2_bf, woT_bf, out, nullptr, nullptr, nullptr, b_out, x, 512, 3);
}

// Round 9
// 518.935 us; speedup vs baseline: 1.1890x; 1.1680x over previous
//
#include <hip/hip_runtime.h>

// Problem constants: b=2, n=8192, DIM=512, HEADS=8, DIM_HEAD=64, M_LAND=256,
// l=32 landmark groups, KS=33. pad==0 and mask all-true -> masking dead code.

typedef __attribute__((ext_vector_type(8))) short bf16x8;
typedef __attribute__((ext_vector_type(4))) float f32x4;

static __device__ __forceinline__ ushort f2bf(float f) {
  union { float f; unsigned u; } c; c.f = f;
  const unsigned r = c.u + 0x7fffu + ((c.u >> 16) & 1u);
  return (ushort)(r >> 16);
}
static __device__ __forceinline__ float bf2f(ushort u) {
  union { unsigned u; float f; } c; c.u = ((unsigned)u) << 16;
  return c.f;
}

// async global->LDS, 16B per lane. LDS dest is wave-uniform base + lane*16.
typedef __attribute__((address_space(1))) const unsigned int guint;
typedef __attribute__((address_space(3))) unsigned int luint;
static __device__ __forceinline__ void gload_lds16(const void* g, void* l) {
  __builtin_amdgcn_global_load_lds((guint*)g, (luint*)l, 16, 0, 0);
}

// ---------------- LayerNorm: one block per row of 512, bf16 output ----------------
__global__ __launch_bounds__(256) void ln_kernel(const float* __restrict__ x,
                                                 const float* __restrict__ w,
                                                 const float* __restrict__ b,
                                                 ushort* __restrict__ xn) {
  const int row = blockIdx.x;
  const int t = threadIdx.x;
  const float* xr = x + (long long)row * 512;
  float v0 = xr[t], v1 = xr[t + 256];
  __shared__ float red[8];
  float s = v0 + v1;
#pragma unroll
  for (int o = 32; o; o >>= 1) s += __shfl_xor(s, o);
  if ((t & 63) == 0) red[t >> 6] = s;
  __syncthreads();
  const float mu = (red[0] + red[1] + red[2] + red[3]) * (1.0f / 512.0f);
  const float d0 = v0 - mu, d1 = v1 - mu;
  float qs = d0 * d0 + d1 * d1;
#pragma unroll
  for (int o = 32; o; o >>= 1) qs += __shfl_xor(qs, o);
  if ((t & 63) == 0) red[4 + (t >> 6)] = qs;
  __syncthreads();
  const float var = (red[4] + red[5] + red[6] + red[7]) * (1.0f / 512.0f);
  const float rs = rsqrtf(var + 1e-5f);
  ushort* xo = xn + (long long)row * 512;
  xo[t] = f2bf(d0 * rs * w[t] + b[t]);
  xo[t + 256] = f2bf(d1 * rs * w[t + 256] + b[t + 256]);
}

// ------------- transpose + convert fp32 [R][Cc] -> bf16 [Cc][R] -------------
__global__ __launch_bounds__(256) void convert_T_bf16(const float* __restrict__ in,
                                                      ushort* __restrict__ out,
                                                      int R, int Cc) {
  const long long i = (long long)blockIdx.x * 256 + threadIdx.x;
  if (i >= (long long)R * Cc) return;
  const int c = (int)(i / R), r = (int)(i % R);
  out[i] = f2bf(in[(long long)r * Cc + c]);
}

// ---------------- bf16 MFMA GEMM: C = A @ Bt^T  (m97 structure) ----------------
// global_load_lds width-16 staging into linear LDS [128][32], 2 barriers/K-step.
// XCD-bijective block swizzle (requires nwg % 8 == 0; holds: 1536 and 512).
// mode 2: qkv scatter -> uq (x0.125), uk, uv bf16 (b,h,n,d), hoisted epilogue.
// mode 3: C[r*512+c] = acc + bias[c] + xres[r*512+c]  (fp32)
__global__ __launch_bounds__(256) void gemm_bf16(
    const ushort* __restrict__ A, const ushort* __restrict__ Bt,
    float* __restrict__ C, ushort* __restrict__ uq, ushort* __restrict__ uk,
    ushort* __restrict__ uv,
    const float* __restrict__ bias, const float* __restrict__ xres,
    int K, int mode) {
  const int tid = threadIdx.x;
  const int wave = tid >> 6, lane = tid & 63;
  const int quad = lane >> 4, l16 = lane & 15;

  // XCD swizzle: consecutive work-ids (sharing an A-panel) land on ONE XCD's L2.
  const int gx = gridDim.x;
  const int nwg = gx * gridDim.y;
  const int hid = blockIdx.y * gx + blockIdx.x;
  const int wid = (hid & 7) * (nwg >> 3) + (hid >> 3);
  const int tm = (wid / gx) * 128, tn = (wid % gx) * 128;

  const int wr = (wave >> 1) * 64, wc = (wave & 1) * 64;
  __shared__ __align__(16) ushort As[128 * 32];
  __shared__ __align__(16) ushort Bs[128 * 32];

  f32x4 acc[4][4];
#pragma unroll
  for (int i = 0; i < 4; ++i)
#pragma unroll
    for (int j = 0; j < 4; ++j) acc[i][j] = (f32x4)0.f;

  // staging: chunk i = call*256 + tid; row = i>>2; col-chunk = (i&3)*8 ushorts
  const int r0 = tid >> 2;
  const int c0 = (tid & 3) * 8;
  const ushort* gA0 = A + (long long)(tm + r0) * K + c0;
  const ushort* gA1 = A + (long long)(tm + 64 + r0) * K + c0;
  const ushort* gB0 = Bt + (long long)(tn + r0) * K + c0;
  const ushort* gB1 = Bt + (long long)(tn + 64 + r0) * K + c0;
  ushort* lA0 = As + (wave * 64) * 8;          // wave-uniform LDS bases
  ushort* lA1 = As + (256 + wave * 64) * 8;
  ushort* lB0 = Bs + (wave * 64) * 8;
  ushort* lB1 = Bs + (256 + wave * 64) * 8;

  for (int kb = 0; kb < K; kb += 32) {
    __syncthreads();
    gload_lds16(gA0 + kb, lA0);
    gload_lds16(gA1 + kb, lA1);
    gload_lds16(gB0 + kb, lB0);
    gload_lds16(gB1 + kb, lB1);
    __syncthreads();
    bf16x8 af[4], bfr[4];
#pragma unroll
    for (int t = 0; t < 4; ++t) {
      af[t] = *(const bf16x8*)&As[(wr + t * 16 + l16) * 32 + quad * 8];
      bfr[t] = *(const bf16x8*)&Bs[(wc + t * 16 + l16) * 32 + quad * 8];
    }
#pragma unroll
    for (int i = 0; i < 4; ++i)
#pragma unroll
      for (int j = 0; j < 4; ++j)
        acc[i][j] = __builtin_amdgcn_mfma_f32_16x16x32_bf16(af[i], bfr[j], acc[i][j], 0, 0, 0);
  }

  if (mode == 2) {
    // hoisted scatter: wave-uniform head, block-uniform batch
    const int gcol = tn + wc;                        // 64-aligned
    const int part = gcol >> 9, hh = (gcol >> 6) & 7;
    const float scale = (part == 0) ? 0.125f : 1.0f; // q * DIM_HEAD^-0.5
    ushort* dst = (part == 0) ? uq : ((part == 1) ? uk : uv);
    ushort* base = dst + ((((long long)((tm >> 13) * 8 + hh)) << 13) +
                          (tm & 8191) + wr + quad * 4) * 64 + l16;
#pragma unroll
    for (int ti = 0; ti < 4; ++ti) {
#pragma unroll
      for (int r = 0; r < 4; ++r) {
        ushort* drow = base + (ti * 16 + r) * 64;
#pragma unroll
        for (int tj = 0; tj < 4; ++tj)
          drow[tj * 16] = f2bf(acc[ti][tj][r] * scale);
      }
    }
  } else {  // mode 3
#pragma unroll
    for (int ti = 0; ti < 4; ++ti) {
#pragma unroll
      for (int r = 0; r < 4; ++r) {
        const long long gr = tm + wr + ti * 16 + quad * 4 + r;
#pragma unroll
        for (int tj = 0; tj < 4; ++tj) {
          const int gc = tn + wc + tj * 16 + l16;
          const long long idx = gr * 512 + gc;
          C[idx] = acc[ti][tj][r] + bias[gc] + xres[idx];
        }
      }
    }
  }
}

// ---------------- fp32 GEMM (sim2 only): C = A@B ----------------
__global__ __launch_bounds__(256) void gemm_f32(
    const float* __restrict__ A, const float* __restrict__ B,
    float* __restrict__ C, int K, int lda, int ldb, int ldc,
    long long sA, long long sB, long long sC) {
  const int tid = threadIdx.x;
  const int batch = blockIdx.z;
  A += (long long)batch * sA;
  B += (long long)batch * sB;
  C += (long long)batch * sC;
  const int tm = blockIdx.y * 64;
  const int tn = blockIdx.x * 64;

  __shared__ float As[16][65];
  __shared__ float Bs[16][65];

  const int tx = tid & 15, ty = tid >> 4;
  const int ar = tid >> 2, ac = (tid & 3) * 4;
  const int br = tid >> 4, bc = (tid & 15) * 4;

  float acc[4][4];
#pragma unroll
  for (int i = 0; i < 4; ++i)
#pragma unroll
    for (int j = 0; j < 4; ++j) acc[i][j] = 0.f;

  for (int kb = 0; kb < K; kb += 16) {
    const float4 a4 = *(const float4*)(A + (long long)(tm + ar) * lda + kb + ac);
    const float4 b4 = *(const float4*)(B + (long long)(kb + br) * ldb + tn + bc);
    __syncthreads();
    As[ac + 0][ar] = a4.x; As[ac + 1][ar] = a4.y;
    As[ac + 2][ar] = a4.z; As[ac + 3][ar] = a4.w;
    Bs[br][bc + 0] = b4.x; Bs[br][bc + 1] = b4.y;
    Bs[br][bc + 2] = b4.z; Bs[br][bc + 3] = b4.w;
    __syncthreads();
#pragma unroll
    for (int kk = 0; kk < 16; ++kk) {
      float av[4], bv[4];
#pragma unroll
      for (int i = 0; i < 4; ++i) av[i] = As[kk][ty * 4 + i];
#pragma unroll
      for (int j = 0; j < 4; ++j) bv[j] = Bs[kk][tx * 4 + j];
#pragma unroll
      for (int i = 0; i < 4; ++i)
#pragma unroll
        for (int j = 0; j < 4; ++j) acc[i][j] = fmaf(av[i], bv[j], acc[i][j]);
    }
  }
#pragma unroll
  for (int i = 0; i < 4; ++i) {
    const long long r = tm + ty * 4 + i;
#pragma unroll
    for (int j = 0; j < 4; ++j) C[r * ldc + tn + tx * 4 + j] = acc[i][j];
  }
}

// -------- split/hi bf16 MFMA batched GEMM stage body for the pinv chain --------
// v2: B tile (32 cols x K=256 = 16 KB) staged ONCE per block into XOR-swizzled
// LDS via global_load_lds (removes the 4x-redundant per-wave B VMEM loads and
// their L2 latency from the inner loop). Swizzle: linear LDS dest + inverse-
// swizzled global source + same XOR on read (involution, rule both-sides).
// A rows stay direct-from-global (per-wave unique, unroll-prefetched).
static __device__ __forceinline__ void stage_body(
    int tc, int tr, int bh,
    const ushort* __restrict__ Ah, const ushort* __restrict__ Al,
    const ushort* __restrict__ BTh, const ushort* __restrict__ BTl,
    const ushort* __restrict__ D1h, const ushort* __restrict__ D1l,
    const ushort* __restrict__ D2h, const ushort* __restrict__ D2l,
    ushort* __restrict__ Ch, ushort* __restrict__ Cl,
    ushort* __restrict__ CTh, ushort* __restrict__ CTl,
    float alpha, float beta1, float beta2,
    long long sBT, long long sC, int ldc,
    ushort* Bsh, ushort* Bsl,
    ushort (*TBh)[36], ushort (*TBl)[36]) {
  const int tid = threadIdx.x;
  const int wave = tid >> 6, lane = tid & 63;
  const int quad = lane >> 4, l16 = lane & 15;
  const bool hasAl = (Al != nullptr);
  const bool hasBl = (BTl != nullptr);

  const ushort* A_h = Ah + (long long)bh * 65536 + (long long)(tr + wave * 16 + l16) * 256;
  const ushort* A_l = (hasAl ? Al : Ah) + (long long)bh * 65536 +
                      (long long)(tr + wave * 16 + l16) * 256;
  const char* Bg_h = (const char*)(BTh + (long long)bh * sBT + (long long)tc * 256);
  const char* Bg_l = (const char*)((hasBl ? BTl : BTh) + (long long)bh * sBT +
                                   (long long)tc * 256);

  // stage B tile: 4 calls x 4 KB; col = byte>>9, src = lin ^ ((col&7)<<4)
#pragma unroll
  for (int c = 0; c < 4; ++c) {
    const int lin = c * 4096 + tid * 16;
    const int src = lin ^ (((lin >> 9) & 7) << 4);
    char* ldst = (char*)Bsh + c * 4096 + wave * 1024;  // wave-uniform base
    gload_lds16(Bg_h + src, ldst);
    if (hasBl) gload_lds16(Bg_l + src, (char*)Bsl + c * 4096 + wave * 1024);
  }
  __syncthreads();

  f32x4 acc[2];
  acc[0] = (f32x4)0.f; acc[1] = (f32x4)0.f;

#pragma unroll
  for (int kc = 0; kc < 8; ++kc) {
    const int ko = kc * 32 + quad * 8;
    const bf16x8 a_h = *(const bf16x8*)(A_h + ko);
    bf16x8 a_l;
    if (hasAl) a_l = *(const bf16x8*)(A_l + ko);
#pragma unroll
    for (int ct = 0; ct < 2; ++ct) {
      const int col = ct * 16 + l16;
      const int lb = (col * 512 + ko * 2) ^ ((col & 7) << 4);
      const bf16x8 b_h = *(const bf16x8*)((const char*)Bsh + lb);
      acc[ct] = __builtin_amdgcn_mfma_f32_16x16x32_bf16(a_h, b_h, acc[ct], 0, 0, 0);
      if (hasBl) {
        const bf16x8 b_l = *(const bf16x8*)((const char*)Bsl + lb);
        acc[ct] = __builtin_amdgcn_mfma_f32_16x16x32_bf16(a_h, b_l, acc[ct], 0, 0, 0);
      }
      if (hasAl)
        acc[ct] = __builtin_amdgcn_mfma_f32_16x16x32_bf16(a_l, b_h, acc[ct], 0, 0, 0);
    }
  }

#pragma unroll
  for (int ct = 0; ct < 2; ++ct) {
#pragma unroll
    for (int r = 0; r < 4; ++r) {
      const int rl = wave * 16 + quad * 4 + r;
      const int clc = ct * 16 + l16;
      float val = alpha * acc[ct][r];
      if (D1h) {
        const long long di = (long long)bh * 65536 + (long long)(tr + rl) * 256 + tc + clc;
        float d = bf2f(D1h[di]);
        if (D1l) d += bf2f(D1l[di]);
        val += beta1 * d;
      }
      if (D2h) {
        const long long di = (long long)bh * 65536 + (long long)(tr + rl) * 256 + tc + clc;
        float d = bf2f(D2h[di]);
        if (D2l) d += bf2f(D2l[di]);
        val += beta2 * d;
      }
      const ushort h = f2bf(val);
      TBh[rl][clc] = h;
      TBl[rl][clc] = f2bf(val - bf2f(h));
    }
  }
  __syncthreads();
  if (Ch) {  // row-major store, coalesced uint4
    const int rl = tid >> 2, seg = (tid & 3) * 8;
    const long long ci = (long long)bh * sC + (long long)(tr + rl) * ldc + tc + seg;
    *(uint4*)&Ch[ci] = *(const uint4*)&TBh[rl][seg];
    if (Cl) *(uint4*)&Cl[ci] = *(const uint4*)&TBl[rl][seg];
  }
  if (CTh) {  // transposed store: gather 8 from LDS, uint4 out
    const int clc = tid >> 3, seg = (tid & 7) * 8;
    union { uint4 u; ushort s[8]; } th, tl;
#pragma unroll
    for (int j = 0; j < 8; ++j) {
      th.s[j] = TBh[seg + j][clc];
      tl.s[j] = TBl[seg + j][clc];
    }
    const long long gi = (long long)bh * 65536 + (long long)(tc + clc) * 256 + tr + seg;
    *(uint4*)&CTh[gi] = th.u;
    if (CTl) *(uint4*)&CTl[gi] = tl.u;
  }
}

// standard stage kernel: grid (cols/32, rows/64, 16)
__global__ __launch_bounds__(256) void gemm_split(
    const ushort* __restrict__ Ah, const ushort* __restrict__ Al,
    const ushort* __restrict__ BTh, const ushort* __restrict__ BTl,
    const ushort* __restrict__ D1h, const ushort* __restrict__ D1l,
    const ushort* __restrict__ D2h, const ushort* __restrict__ D2l,
    ushort* __restrict__ Ch, ushort* __restrict__ Cl,
    ushort* __restrict__ CTh, ushort* __restrict__ CTl,
    float alpha, float beta1, float beta2,
    long long sBT, long long sC, int ldc) {
  __shared__ __align__(16) ushort Bsh[8192];
  __shared__ __align__(16) ushort Bsl[8192];
  __shared__ ushort TBh[64][36];
  __shared__ ushort TBl[64][36];
  stage_body(blockIdx.x * 32, blockIdx.y * 64, blockIdx.z,
             Ah, Al, BTh, BTl, D1h, D1l, D2h, D2l, Ch, Cl, CTh, CTl,
             alpha, beta1, beta2, sBT, sC, ldc, Bsh, Bsl, TBh, TBl);
}

// dual-update kernel: one launch computes BOTH  z' = -0.25 z@T2 + 3.25 z  and
// Y' = -0.25 Y@T2 + 3.25 Y. grid (8, 8, 16): y<4 -> z rows, y>=4 -> Y rows.
// hasBl always false here -> single B staging buffer.
__global__ __launch_bounds__(256) void gemm_dual(
    const ushort* __restrict__ zA, const ushort* __restrict__ yA,
    const ushort* __restrict__ BT,
    ushort* __restrict__ zC, ushort* __restrict__ zCT,
    ushort* __restrict__ yC, ushort* __restrict__ yCT) {
  __shared__ __align__(16) ushort Bsh[8192];
  __shared__ ushort TBh[64][36];
  __shared__ ushort TBl[64][36];
  const int by = blockIdx.y;
  if (by < 4)
    stage_body(blockIdx.x * 32, by * 64, blockIdx.z,
               zA, nullptr, BT, nullptr, zA, nullptr, nullptr, nullptr,
               zC, nullptr, zCT, nullptr, -0.25f, 3.25f, 0.f,
               65536, 65536, 256, Bsh, Bsh, TBh, TBl);
  else
    stage_body(blockIdx.x * 32, (by - 4) * 64, blockIdx.z,
               yA, nullptr, BT, nullptr, yA, nullptr, nullptr, nullptr,
               yC, nullptr, yCT, nullptr, -0.25f, 3.25f, 0.f,
               65536, 65536, 256, Bsh, Bsh, TBh, TBl);
}

// ------------- landmark means from bf16 q,k -------------
__global__ __launch_bounds__(64) void landmark_kernel(
    const ushort* __restrict__ q, const ushort* __restrict__ k,
    float* __restrict__ qlf, float* __restrict__ klTf,
    ushort* __restrict__ qlb, ushort* __restrict__ klb) {
  const int bh = blockIdx.y, i = blockIdx.x, d = threadIdx.x;
  const long long base = (((long long)bh << 13) + i * 32) * 64 + d;
  float sq = 0.f, sk = 0.f;
#pragma unroll
  for (int j = 0; j < 32; ++j) {
    sq += bf2f(q[base + j * 64]);
    sk += bf2f(k[base + j * 64]);
  }
  const float mq = sq * (1.0f / 32.0f), mk = sk * (1.0f / 32.0f);
  qlf[((long long)bh * 256 + i) * 64 + d] = mq;
  klTf[((long long)bh * 64 + d) * 256 + i] = mk;
  qlb[((long long)bh * 256 + i) * 64 + d] = f2bf(mq);
  klb[((long long)bh * 256 + i) * 64 + d] = f2bf(mk);
}

// ---------------- softmax over rows of length 256: wave per row ----------------
__global__ __launch_bounds__(256) void softmax256(float* __restrict__ a) {
  const long long row = (long long)blockIdx.x * 4 + (threadIdx.x >> 6);
  const int lane = threadIdx.x & 63;
  float* p = a + row * 256 + lane * 4;
  float4 vv = *(float4*)p;
  float m = fmaxf(fmaxf(vv.x, vv.y), fmaxf(vv.z, vv.w));
#pragma unroll
  for (int o = 32; o; o >>= 1) m = fmaxf(m, __shfl_xor(m, o));
  vv.x = __expf(vv.x - m); vv.y = __expf(vv.y - m);
  vv.z = __expf(vv.z - m); vv.w = __expf(vv.w - m);
  float s = vv.x + vv.y + vv.z + vv.w;
#pragma unroll
  for (int o = 32; o; o >>= 1) s += __shfl_xor(s, o);
  const float inv = 1.0f / s;
  vv.x *= inv; vv.y *= inv; vv.z *= inv; vv.w *= inv;
  *(float4*)p = vv;
}

// ---------------- bf16 MFMA flash attention: Out = softmax(Q K^T) V ----------------
// nsplit==1 && CV==null: writes bf16 to Out (ushort*), sO in elements.
// nsplit==1 && CV!=null: fused epilogue -- adds conv residual CV (b,h,n,d) and
//   writes directly into (b*n, 512) layout at Out (ushort*), col block h*64.
__global__ __launch_bounds__(256) void flash_mfma(
    const ushort* __restrict__ Q, const ushort* __restrict__ K,
    const ushort* __restrict__ V, float* __restrict__ Out,
    const ushort* __restrict__ CV,
    float* __restrict__ Opart, float* __restrict__ Mpart,
    float* __restrict__ Lpart,
    long long sQ, long long sK, long long sV, long long sO,
    int iters, int nsplit) {
  const int bh = blockIdx.z, mt = blockIdx.y, ns = blockIdx.x;
  const int tid = threadIdx.x;
  const int wave = tid >> 6, lane = tid & 63;
  const int quad = lane >> 4, l16 = lane & 15;
  __shared__ ushort Vt[64][72];  // [d][key]
  __shared__ ushort Ps[64][72];  // [q-row][key]

  const ushort* Qb = Q + (long long)bh * sQ + (long long)(mt * 64) * 64;
  const ushort* Kb = K + (long long)bh * sK + (long long)(ns * iters * 64) * 64;
  const ushort* Vb = V + (long long)bh * sV + (long long)(ns * iters * 64) * 64;

  bf16x8 aq[2];
#pragma unroll
  for (int kc = 0; kc < 2; ++kc)
    aq[kc] = *(const bf16x8*)(Qb + (long long)(wave * 16 + l16) * 64 + kc * 32 + quad * 8);

  f32x4 acc[4];
  float mrow[4], lrow[4];
#pragma unroll
  for (int dt = 0; dt < 4; ++dt) acc[dt] = (f32x4)0.f;
#pragma unroll
  for (int r = 0; r < 4; ++r) { mrow[r] = -1e30f; lrow[r] = 0.f; }

  for (int it = 0; it < iters; ++it) {
    __syncthreads();
    for (int i = tid; i < 512; i += 256) {
      const int key = i & 63, c8 = (i >> 6) * 8;
      union { uint4 u; ushort s[8]; } t;
      t.u = *(const uint4*)(Vb + (long long)(it * 64 + key) * 64 + c8);
#pragma unroll
      for (int j = 0; j < 8; ++j) Vt[c8 + j][key] = t.s[j];
    }
    f32x4 sfr[4];
#pragma unroll
    for (int kt = 0; kt < 4; ++kt) {
      sfr[kt] = (f32x4)0.f;
#pragma unroll
      for (int kc = 0; kc < 2; ++kc) {
        const bf16x8 bk = *(const bf16x8*)(Kb +
            (long long)(it * 64 + kt * 16 + l16) * 64 + kc * 32 + quad * 8);
        sfr[kt] = __builtin_amdgcn_mfma_f32_16x16x32_bf16(aq[kc], bk, sfr[kt], 0, 0, 0);
      }
    }
#pragma unroll
    for (int r = 0; r < 4; ++r) {
      float rm = fmaxf(fmaxf(sfr[0][r], sfr[1][r]), fmaxf(sfr[2][r], sfr[3][r]));
#pragma unroll
      for (int off = 1; off < 16; off <<= 1) rm = fmaxf(rm, __shfl_xor(rm, off));
      const float mn = fmaxf(mrow[r], rm);
      const float scv = __expf(mrow[r] - mn);
      float rs = 0.f;
#pragma unroll
      for (int kt = 0; kt < 4; ++kt) {
        const float p = __expf(sfr[kt][r] - mn);
        sfr[kt][r] = p;
        rs += p;
      }
#pragma unroll
      for (int off = 1; off < 16; off <<= 1) rs += __shfl_xor(rs, off);
      lrow[r] = lrow[r] * scv + rs;
      mrow[r] = mn;
#pragma unroll
      for (int dt = 0; dt < 4; ++dt) acc[dt][r] *= scv;
#pragma unroll
      for (int kt = 0; kt < 4; ++kt)
        Ps[wave * 16 + quad * 4 + r][kt * 16 + l16] = f2bf(sfr[kt][r]);
    }
    __syncthreads();
#pragma unroll
    for (int kc = 0; kc < 2; ++kc) {
      const bf16x8 ap = *(const bf16x8*)&Ps[wave * 16 + l16][kc * 32 + quad * 8];
#pragma unroll
      for (int dt = 0; dt < 4; ++dt) {
        const bf16x8 bv = *(const bf16x8*)&Vt[dt * 16 + l16][kc * 32 + quad * 8];
        acc[dt] = __builtin_amdgcn_mfma_f32_16x16x32_bf16(ap, bv, acc[dt], 0, 0, 0);
      }
    }
  }

  if (nsplit == 1) {
    if (CV) {  // fused: add conv residual, write (b*n, 512) layout
      const int b = bh >> 3, h = bh & 7;
      const ushort* cvb = CV + (((long long)bh << 13) + mt * 64) * 64;
      ushort* Ob = (ushort*)Out + ((long long)(b * 8192 + mt * 64)) * 512 + h * 64;
#pragma unroll
      for (int r = 0; r < 4; ++r) {
        const float inv = 1.0f / lrow[r];
        const int row = wave * 16 + quad * 4 + r;
#pragma unroll
        for (int dt = 0; dt < 4; ++dt) {
          const int col = dt * 16 + l16;
          const float val = acc[dt][r] * inv + bf2f(cvb[(long long)row * 64 + col]);
          Ob[(long long)row * 512 + col] = f2bf(val);
        }
      }
    } else {
      ushort* Ob = (ushort*)Out + (long long)bh * sO + (long long)(mt * 64) * 64;
#pragma unroll
      for (int r = 0; r < 4; ++r) {
        const float inv = 1.0f / lrow[r];
        const int row = wave * 16 + quad * 4 + r;
#pragma unroll
        for (int dt = 0; dt < 4; ++dt)
          Ob[(long long)row * 64 + dt * 16 + l16] = f2bf(acc[dt][r] * inv);
      }
    }
  } else {
    const long long pbase = ((long long)(bh * gridDim.y + mt) * nsplit + ns);
    const int row0 = wave * 16 + quad * 4;
#pragma unroll
    for (int r = 0; r < 4; ++r) {
#pragma unroll
      for (int dt = 0; dt < 4; ++dt)
        Opart[(pbase * 64 + row0 + r) * 64 + dt * 16 + l16] = acc[dt][r];
      if (l16 == 0) {
        Mpart[pbase * 64 + row0 + r] = mrow[r];
        Lpart[pbase * 64 + row0 + r] = lrow[r];
      }
    }
  }
}

// ------- merge flash partials -> a3v^T hi/lo bf16 [bh][64][256]; 1024 blocks -------
__global__ __launch_bounds__(256) void flash_merge(
    const float* __restrict__ Opart, const float* __restrict__ Mpart,
    const float* __restrict__ Lpart, ushort* __restrict__ a3vTh,
    ushort* __restrict__ a3vTl, int nsplit) {
  const int bm = blockIdx.x >> 4;  // bh*4 + mt
  const int rg = blockIdx.x & 15;  // 4-row group
  const int bh = bm >> 2, mt = bm & 3;
  const int c = threadIdx.x & 63, rb = threadIdx.x >> 6;
  const int r = rg * 4 + rb;
  float ms = -1e30f;
  for (int ns = 0; ns < nsplit; ++ns)
    ms = fmaxf(ms, Mpart[(bm * nsplit + ns) * 64 + r]);
  float L = 0.f, O = 0.f;
  for (int ns = 0; ns < nsplit; ++ns) {
    const float w = __expf(Mpart[(bm * nsplit + ns) * 64 + r] - ms);
    L += w * Lpart[(bm * nsplit + ns) * 64 + r];
    O += w * Opart[((long long)(bm * nsplit + ns) * 64 + r) * 64 + c];
  }
  const float val = O / L;
  const ushort h = f2bf(val);
  const long long ti = (long long)bh * 16384 + (long long)c * 256 + mt * 64 + r;
  a3vTh[ti] = h;
  a3vTl[ti] = f2bf(val - bf2f(h));
}

// ------- pm init + a2 row/col-sum global maxes (atomicMax on positive floats) -------
__global__ void pm_init(float* __restrict__ pm) {
  if (threadIdx.x < 2) pm[threadIdx.x] = 0.f;
}

__global__ __launch_bounds__(256) void a2_sums(const float* __restrict__ a2,
                                               float* __restrict__ pm) {
  // grid (8, 16): p = 32-row/col slice, bh
  const int p = blockIdx.x, bh = blockIdx.y;
  const float* m = a2 + (long long)bh * 65536;
  const int tid = threadIdx.x;
  __shared__ float red[4];
  {  // row sums: 8 threads per row, 32 elems each
    const int r = p * 32 + (tid >> 3);
    const int c0 = (tid & 7) * 32;
    float s = 0.f;
#pragma unroll 8
    for (int j = 0; j < 32; ++j) s += m[r * 256 + c0 + j];
    s += __shfl_xor(s, 1); s += __shfl_xor(s, 2); s += __shfl_xor(s, 4);
    float mx = s;
#pragma unroll
    for (int o = 8; o < 64; o <<= 1) mx = fmaxf(mx, __shfl_xor(mx, o));
    if ((tid & 63) == 0) red[tid >> 6] = mx;
    __syncthreads();
    if (tid == 0) {
      mx = fmaxf(fmaxf(red[0], red[1]), fmaxf(red[2], red[3]));
      atomicMax((int*)&pm[0], __float_as_int(mx));
    }
    __syncthreads();
  }
  {  // col sums: 8 threads per col, 32 rows each
    const int c = p * 32 + (tid >> 3);
    const int r0 = (tid & 7) * 32;
    float s = 0.f;
#pragma unroll 8
    for (int j = 0; j < 32; ++j) s += m[(r0 + j) * 256 + c];
    s += __shfl_xor(s, 1); s += __shfl_xor(s, 2); s += __shfl_xor(s, 4);
    float mx = s;
#pragma unroll
    for (int o = 8; o < 64; o <<= 1) mx = fmaxf(mx, __shfl_xor(mx, o));
    if ((tid & 63) == 0) red[tid >> 6] = mx;
    __syncthreads();
    if (tid == 0) {
      mx = fmaxf(fmaxf(red[0], red[1]), fmaxf(red[2], red[3]));
      atomicMax((int*)&pm[1], __float_as_int(mx));
    }
  }
}

// ---- pinv init: split a2 -> hi/lo; z0 = a2^T * s (hi row-major + hi transposed) ----
__global__ __launch_bounds__(256) void pinv_init(
    const float* __restrict__ a2, const float* __restrict__ pm,
    ushort* __restrict__ a2h, ushort* __restrict__ a2l,
    ushort* __restrict__ zh, ushort* __restrict__ zTh) {
  const int bh = blockIdx.y;
  const float s = 1.0f / (pm[0] * pm[1]);
  const long long base = (long long)bh * 65536;
  const int i0 = blockIdx.x * 4096;
  for (int t = threadIdx.x; t < 4096; t += 256) {
    const int idx = i0 + t;
    const float v = a2[base + idx];
    const ushort h = f2bf(v);
    a2h[base + idx] = h;
    a2l[base + idx] = f2bf(v - bf2f(h));
    zTh[base + idx] = f2bf(v * s);  // zT = a2 * s
    const float vt = a2[base + ((long long)(idx & 255) << 8) + (idx >> 8)] * s;
    zh[base + idx] = f2bf(vt);
  }
}

// -------- depthwise conv (KS=33) from bf16 v -> cv (bf16, (b,h,n,d)) --------
__global__ __launch_bounds__(256) void conv_store(const ushort* __restrict__ v,
                                                  const float* __restrict__ w,
                                                  ushort* __restrict__ cv) {
  const int bh = blockIdx.y;
  const int n0 = blockIdx.x * 128;
  const int h = bh & 7;
  __shared__ float vs[160][64];
  __shared__ float ws[33];
  if (threadIdx.x < 33) ws[threadIdx.x] = w[h * 33 + threadIdx.x];
  for (int i = threadIdx.x; i < 160 * 8; i += 256) {
    const int r = i >> 3, c8 = (i & 7) * 8;
    const int n = n0 - 16 + r;
    if (n >= 0 && n < 8192) {
      union { uint4 u; ushort s[8]; } t;
      t.u = *(const uint4*)(v + (((long long)bh << 13) + n) * 64 + c8);
#pragma unroll
      for (int j = 0; j < 8; ++j) vs[r][c8 + j] = bf2f(t.s[j]);
    } else {
#pragma unroll
      for (int j = 0; j < 8; ++j) vs[r][c8 + j] = 0.f;
    }
  }
  __syncthreads();
  const int d = threadIdx.x & 63, r0 = threadIdx.x >> 6;
  for (int rr = r0; rr < 128; rr += 4) {
    float acc = 0.f;
#pragma unroll
    for (int kk = 0; kk < 33; ++kk) acc += ws[kk] * vs[rr + kk][d];
    cv[(((long long)bh << 13) + n0 + rr) * 64 + d] = f2bf(acc);
  }
}

// ---------------- host ----------------
static inline void launch_split(hipStream_t st, int gridX,
    const ushort* Ah, const ushort* Al,
    const ushort* BTh, const ushort* BTl, long long sBT,
    const ushort* D1h, const ushort* D1l, float beta1,
    const ushort* D2h, const ushort* D2l, float beta2,
    ushort* Ch, ushort* Cl, ushort* CTh, ushort* CTl,
    long long sC, int ldc, float alpha) {
  dim3 grid((unsigned)gridX, 4, 16);
  hipLaunchKernelGGL(gemm_split, grid, dim3(256), 0, st, Ah, Al, BTh, BTl,
                     D1h, D1l, D2h, D2l, Ch, Cl, CTh, CTl,
                     alpha, beta1, beta2, sBT, sC, ldc);
}

extern "C" void kernel_launch(void* const* d_in, const int* in_sizes, int n_in,
                              void* d_out, int out_size, void* d_ws, size_t ws_size,
                              hipStream_t stream) {
  const float* x = (const float*)d_in[0];
  // d_in[1] = mask: all-true -> unused
  const float* ln_w = (const float*)d_in[2];
  const float* ln_b = (const float*)d_in[3];
  const float* w_qkv = (const float*)d_in[4];
  const float* w_out = (const float*)d_in[5];
  const float* b_out = (const float*)d_in[6];
  const float* conv_w = (const float*)d_in[7];
  float* out = (float*)d_out;

  float* ws = (float*)d_ws;
  // Region R (10,485,760 floats = 40 MB), time-multiplexed:
  //   phase A: Opart/Mpart/Lpart; phase B: pinv chain; phase C: ao2 + cv (bf16)
  float* R = ws;
  float* a2   = R + 10485760LL;        // 1048576 fp32
  float* qlf  = a2 + 1048576LL;        // 262144
  float* klTf = qlf + 262144LL;        // 262144
  float* pm   = klTf + 262144LL;       // 64
  ushort* q_bf   = (ushort*)(pm + 64); // 8388608 each
  ushort* k_bf   = q_bf + 8388608LL;
  ushort* v_bf   = k_bf + 8388608LL;
  ushort* xn_bf  = v_bf + 8388608LL;
  ushort* ql_bf  = xn_bf + 8388608LL;  // 262144
  ushort* kl_bf  = ql_bf + 262144LL;
  ushort* tb_bf  = kl_bf + 262144LL;   // 262144
  ushort* wqT_bf = tb_bf + 262144LL;   // 786432
  ushort* woT_bf = wqT_bf + 786432LL;  // 262144
  ushort* a2h    = woT_bf + 262144LL;  // 1048576 each
  ushort* a2l    = a2h + 1048576LL;
  ushort* a3vTh  = a2l + 1048576LL;    // 262144 each
  ushort* a3vTl  = a3vTh + 262144LL;

  // phase A (nsplit=16): Opart 4,194,304 fp32 (16 MB) + M/L 65,536 each
  float* Opart = R;
  float* Mpart = R + 4194304LL;
  float* Lpart = R + 4194304LL + 65536;
  // phase B: chain arrays (each 1,048,576 ushorts)
  ushort* cb = (ushort*)R;
  ushort* zah = cb;                ushort* zal = cb + 1048576LL;
  ushort* zaTh = cb + 2097152LL;
  ushort* zbh = cb + 4194304LL;
  ushort* zbTh = cb + 6291456LL;
  ushort* Ph = cb + 8388608LL;     ushort* Pl = cb + 9437184LL;
  ushort* PTh = cb + 10485760LL;   ushort* PTl = cb + 11534336LL;
  ushort* P2h = cb + 12582912LL;   ushort* P2l = cb + 13631488LL;
  ushort* P2Th = cb + 14680064LL;  ushort* P2Tl = cb + 15728640LL;
  ushort* T2Th = cb + 18874368LL;  ushort* T2Tl = cb + 19922944LL;
  // Y recurrence buffers (hi-only iters): live in lo-regions unused before split
  ushort* Yah = Pl;    ushort* YaTh = PTl;
  ushort* Ybh = P2l;   ushort* YbTh = P2Tl;
  // phase C: fused attn output (b*n,512) + conv buffer
  ushort* ao2_bf = (ushort*)R;                  // 8388608 ushorts
  ushort* cv_bf  = (ushort*)R + 8388608LL;      // 8388608 ushorts

  // 0. weight transposes + bf16 convert
  hipLaunchKernelGGL(convert_T_bf16, dim3(3072), dim3(256), 0, stream,
                     w_qkv, wqT_bf, 512, 1536);
  hipLaunchKernelGGL(convert_T_bf16, dim3(1024), dim3(256), 0, stream,
                     w_out, woT_bf, 512, 512);
  // 1. LayerNorm -> bf16
  hipLaunchKernelGGL(ln_kernel, dim3(16384), dim3(256), 0, stream, x, ln_w, ln_b, xn_bf);
  // 2. qkv GEMM (MFMA), scatter q(x0.125),k,v as bf16 (b,h,n,d), hoisted epilogue
  hipLaunchKernelGGL(gemm_bf16, dim3(12, 128), dim3(256), 0, stream,
                     xn_bf, wqT_bf, nullptr, q_bf, k_bf, v_bf, nullptr, nullptr, 512, 2);
  // 3. landmarks
  hipLaunchKernelGGL(landmark_kernel, dim3(256, 16), dim3(64), 0, stream,
                     q_bf, k_bf, qlf, klTf, ql_bf, kl_bf);
  // 4. sim2 = ql @ klT -> a2 (fp32) ; softmax
  {
    dim3 g(4, 4, 16);
    hipLaunchKernelGGL(gemm_f32, g, dim3(256), 0, stream, qlf, klTf, a2,
                       64, 64, 256, 256, 16384LL, 16384LL, 65536LL);
  }
  hipLaunchKernelGGL(softmax256, dim3(1024), dim3(256), 0, stream, a2);
  // 5. a3v = softmax(ql @ k^T) @ v  -- MFMA flash, nsplit=16 (4 blocks/CU), merge
  hipLaunchKernelGGL(flash_mfma, dim3(16, 4, 16), dim3(256), 0, stream,
                     ql_bf, k_bf, v_bf, (float*)nullptr, (const ushort*)nullptr,
                     Opart, Mpart, Lpart,
                     16384LL, 524288LL, 524288LL, 0LL, 8, 16);
  hipLaunchKernelGGL(flash_merge, dim3(1024), dim3(256), 0, stream,
                     Opart, Mpart, Lpart, a3vTh, a3vTl, 16);
  // 6. pinv of a2 via Newton-Schulz; Y-recurrence saves the per-iter a2@z launch
  hipLaunchKernelGGL(pm_init, dim3(1), dim3(64), 0, stream, pm);
  hipLaunchKernelGGL(a2_sums, dim3(8, 16), dim3(256), 0, stream, a2, pm);
  hipLaunchKernelGGL(pinv_init, dim3(16, 16), dim3(256), 0, stream, a2, pm,
                     a2h, a2l, zah, zaTh);
  // Y0 = a2 @ z0
  launch_split(stream, 8, a2h, nullptr, zaTh, nullptr, 65536,
               nullptr, nullptr, 0.f, nullptr, nullptr, 0.f,
               Yah, nullptr, YaTh, nullptr, 65536, 256, 1.f);
  {
    ushort *zh = zah, *zTh = zaTh, *zwh = zbh, *zwTh = zbTh;
    ushort *Yh = Yah, *YTh = YaTh, *Ywh = Ybh, *YwTh = YbTh;
    for (int it = 0; it < 5; ++it) {
      // P2 = Y^2
      launch_split(stream, 8, Yh, nullptr, YTh, nullptr, 65536,
                   nullptr, nullptr, 0.f, nullptr, nullptr, 0.f,
                   P2h, nullptr, P2Th, nullptr, 65536, 256, 1.f);
      // T2 = Y@P2 + 15Y - 7P2 (transposed out)
      launch_split(stream, 8, Yh, nullptr, P2Th, nullptr, 65536,
                   Yh, nullptr, 15.f, P2h, nullptr, -7.f,
                   nullptr, nullptr, T2Th, nullptr, 65536, 256, 1.f);
      if (it < 4) {  // dual update: z' and Y' in one launch
        hipLaunchKernelGGL(gemm_dual, dim3(8, 8, 16), dim3(256), 0, stream,
                           zh, Yh, T2Th, zwh, zwTh, Ywh, YwTh);
        ushort* t;
        t = zh; zh = zwh; zwh = t;  t = zTh; zTh = zwTh; zwTh = t;
        t = Yh; Yh = Ywh; Ywh = t;  t = YTh; YTh = YwTh; YwTh = t;
      } else {       // last hi iter: z-only update (Y no longer needed)
        launch_split(stream, 8, zh, nullptr, T2Th, nullptr, 65536,
                     zh, nullptr, 3.25f, nullptr, nullptr, 0.f,
                     zwh, nullptr, zwTh, nullptr, 65536, 256, -0.25f);
      }
    }
  }
  // final iteration: full split precision, fresh P = a2@z5 (z5 = zbh/zbTh)
  launch_split(stream, 8, a2h, a2l, zbTh, nullptr, 65536,
               nullptr, nullptr, 0.f, nullptr, nullptr, 0.f,
               Ph, Pl, PTh, PTl, 65536, 256, 1.f);
  launch_split(stream, 8, Ph, Pl, PTh, PTl, 65536,
               nullptr, nullptr, 0.f, nullptr, nullptr, 0.f,
               P2h, P2l, P2Th, P2Tl, 65536, 256, 1.f);
  launch_split(stream, 8, Ph, Pl, P2Th, P2Tl, 65536,
               Ph, Pl, 15.f, P2h, P2l, -7.f,
               nullptr, nullptr, T2Th, T2Tl, 65536, 256, 1.f);
  launch_split(stream, 8, zbh, nullptr, T2Th, T2Tl, 65536,
               zbh, nullptr, 3.25f, nullptr, nullptr, 0.f,
               zah, zal, nullptr, nullptr, 65536, 256, -0.25f);
  // 7. tb = z6 @ a3v  (split; hi-only bf16 output)
  launch_split(stream, 2, zah, zal, a3vTh, a3vTl, 16384,
               nullptr, nullptr, 0.f, nullptr, nullptr, 0.f,
               tb_bf, nullptr, nullptr, nullptr, 16384, 64, 1.f);
  // 8. depthwise conv residual -> cv (bf16); overwrites dead P-region of chain
  hipLaunchKernelGGL(conv_store, dim3(64, 16), dim3(256), 0, stream, v_bf, conv_w, cv_bf);
  // 9. out1 = softmax(q @ kl^T) @ tb  -- MFMA flash, fused +cv, (b*n,512) bf16 out
  hipLaunchKernelGGL(flash_mfma, dim3(1, 128, 16), dim3(256), 0, stream,
                     q_bf, kl_bf, tb_bf, (float*)ao2_bf, cv_bf,
                     (float*)nullptr, (float*)nullptr, (float*)nullptr,
                     524288LL, 16384LL, 16384LL, 0LL, 4, 1);
  // 10. final: out = ao2 @ w_out + b_out + x (MFMA)
  hipLaunchKernelGGL(gemm_bf16, dim3(4, 128), dim3(256), 0, stream,
                     ao2_bf, woT_bf, out, nullptr, nullptr, nullptr, b_out, x, 512, 3);
}

// Round 10
// 506.205 us; speedup vs baseline: 1.2189x; 1.0251x over previous
//
#include <hip/hip_runtime.h>

// Problem constants: b=2, n=8192, DIM=512, HEADS=8, DIM_HEAD=64, M_LAND=256,
// l=32 landmark groups, KS=33. pad==0 and mask all-true -> masking dead code.

typedef __attribute__((ext_vector_type(8))) short bf16x8;
typedef __attribute__((ext_vector_type(4))) float f32x4;

static __device__ __forceinline__ ushort f2bf(float f) {
  union { float f; unsigned u; } c; c.f = f;
  const unsigned r = c.u + 0x7fffu + ((c.u >> 16) & 1u);
  return (ushort)(r >> 16);
}
static __device__ __forceinline__ float bf2f(ushort u) {
  union { unsigned u; float f; } c; c.u = ((unsigned)u) << 16;
  return c.f;
}

// async global->LDS, 16B per lane. LDS dest is wave-uniform base + lane*16.
typedef __attribute__((address_space(1))) const unsigned int guint;
typedef __attribute__((address_space(3))) unsigned int luint;
static __device__ __forceinline__ void gload_lds16(const void* g, void* l) {
  __builtin_amdgcn_global_load_lds((guint*)g, (luint*)l, 16, 0, 0);
}

// ---------------- LayerNorm: one block per row of 512, bf16 output ----------------
__global__ __launch_bounds__(256) void ln_kernel(const float* __restrict__ x,
                                                 const float* __restrict__ w,
                                                 const float* __restrict__ b,
                                                 ushort* __restrict__ xn) {
  const int row = blockIdx.x;
  const int t = threadIdx.x;
  const float* xr = x + (long long)row * 512;
  float v0 = xr[t], v1 = xr[t + 256];
  __shared__ float red[8];
  float s = v0 + v1;
#pragma unroll
  for (int o = 32; o; o >>= 1) s += __shfl_xor(s, o);
  if ((t & 63) == 0) red[t >> 6] = s;
  __syncthreads();
  const float mu = (red[0] + red[1] + red[2] + red[3]) * (1.0f / 512.0f);
  const float d0 = v0 - mu, d1 = v1 - mu;
  float qs = d0 * d0 + d1 * d1;
#pragma unroll
  for (int o = 32; o; o >>= 1) qs += __shfl_xor(qs, o);
  if ((t & 63) == 0) red[4 + (t >> 6)] = qs;
  __syncthreads();
  const float var = (red[4] + red[5] + red[6] + red[7]) * (1.0f / 512.0f);
  const float rs = rsqrtf(var + 1e-5f);
  ushort* xo = xn + (long long)row * 512;
  xo[t] = f2bf(d0 * rs * w[t] + b[t]);
  xo[t + 256] = f2bf(d1 * rs * w[t + 256] + b[t + 256]);
}

// ------------- transpose + convert fp32 [R][Cc] -> bf16 [Cc][R] -------------
__global__ __launch_bounds__(256) void convert_T_bf16(const float* __restrict__ in,
                                                      ushort* __restrict__ out,
                                                      int R, int Cc) {
  const long long i = (long long)blockIdx.x * 256 + threadIdx.x;
  if (i >= (long long)R * Cc) return;
  const int c = (int)(i / R), r = (int)(i % R);
  out[i] = f2bf(in[(long long)r * Cc + c]);
}

// ---------------- bf16 MFMA GEMM: C = A @ Bt^T  (m97 structure, 8-wave) ----------------
// 512 threads / 8 waves per 128x128 tile: wave = 64x32 output (acc 32 AGPR,
// half the register pressure of the 4-wave form -> 2x occupancy). One
// global_load_lds call per matrix per K-step (512 lanes x 16B = full 8 KB tile).
// XCD-bijective block swizzle (requires nwg % 8 == 0; holds: 1536 and 512).
// mode 2: qkv scatter -> uq (x0.125), uk, uv bf16 (b,h,n,d), hoisted epilogue.
// mode 3: C[r*512+c] = acc + bias[c] + xres[r*512+c]  (fp32)
__global__ __launch_bounds__(512) void gemm_bf16(
    const ushort* __restrict__ A, const ushort* __restrict__ Bt,
    float* __restrict__ C, ushort* __restrict__ uq, ushort* __restrict__ uk,
    ushort* __restrict__ uv,
    const float* __restrict__ bias, const float* __restrict__ xres,
    int K, int mode) {
  const int tid = threadIdx.x;
  const int wave = tid >> 6, lane = tid & 63;
  const int quad = lane >> 4, l16 = lane & 15;

  // XCD swizzle: consecutive work-ids (sharing an A-panel) land on ONE XCD's L2.
  const int gx = gridDim.x;
  const int nwg = gx * gridDim.y;
  const int hid = blockIdx.y * gx + blockIdx.x;
  const int wid = (hid & 7) * (nwg >> 3) + (hid >> 3);
  const int tm = (wid / gx) * 128, tn = (wid % gx) * 128;

  const int wr = (wave >> 2) * 64, wc = (wave & 3) * 32;
  __shared__ __align__(16) ushort As[128 * 32];
  __shared__ __align__(16) ushort Bs[128 * 32];

  f32x4 acc[4][2];
#pragma unroll
  for (int i = 0; i < 4; ++i)
#pragma unroll
    for (int j = 0; j < 2; ++j) acc[i][j] = (f32x4)0.f;

  // staging: chunk i = tid; row = i>>2; col-chunk = (i&3)*8 ushorts (full tile/call)
  const int r0 = tid >> 2;
  const int c0 = (tid & 3) * 8;
  const ushort* gA = A + (long long)(tm + r0) * K + c0;
  const ushort* gB = Bt + (long long)(tn + r0) * K + c0;
  ushort* lA = As + wave * 512;  // wave-uniform LDS base (lane part = lane*16B)
  ushort* lB = Bs + wave * 512;

  for (int kb = 0; kb < K; kb += 32) {
    __syncthreads();
    gload_lds16(gA + kb, lA);
    gload_lds16(gB + kb, lB);
    __syncthreads();
    bf16x8 af[4], bfr[2];
#pragma unroll
    for (int t = 0; t < 4; ++t)
      af[t] = *(const bf16x8*)&As[(wr + t * 16 + l16) * 32 + quad * 8];
#pragma unroll
    for (int u = 0; u < 2; ++u)
      bfr[u] = *(const bf16x8*)&Bs[(wc + u * 16 + l16) * 32 + quad * 8];
#pragma unroll
    for (int i = 0; i < 4; ++i)
#pragma unroll
      for (int j = 0; j < 2; ++j)
        acc[i][j] = __builtin_amdgcn_mfma_f32_16x16x32_bf16(af[i], bfr[j], acc[i][j], 0, 0, 0);
  }

  if (mode == 2) {
    // hoisted scatter: wave-uniform head (32-col span within one 64-col head)
    const int gcol = tn + wc;                        // 32-aligned
    const int part = gcol >> 9, hh = (gcol >> 6) & 7;
    const float scale = (part == 0) ? 0.125f : 1.0f; // q * DIM_HEAD^-0.5
    ushort* dst = (part == 0) ? uq : ((part == 1) ? uk : uv);
    ushort* base = dst + ((((long long)((tm >> 13) * 8 + hh)) << 13) +
                          (tm & 8191) + wr + quad * 4) * 64 + (gcol & 63) + l16;
#pragma unroll
    for (int ti = 0; ti < 4; ++ti) {
#pragma unroll
      for (int r = 0; r < 4; ++r) {
        ushort* drow = base + (ti * 16 + r) * 64;
#pragma unroll
        for (int tj = 0; tj < 2; ++tj)
          drow[tj * 16] = f2bf(acc[ti][tj][r] * scale);
      }
    }
  } else {  // mode 3
#pragma unroll
    for (int ti = 0; ti < 4; ++ti) {
#pragma unroll
      for (int r = 0; r < 4; ++r) {
        const long long gr = tm + wr + ti * 16 + quad * 4 + r;
#pragma unroll
        for (int tj = 0; tj < 2; ++tj) {
          const int gc = tn + wc + tj * 16 + l16;
          const long long idx = gr * 512 + gc;
          C[idx] = acc[ti][tj][r] + bias[gc] + xres[idx];
        }
      }
    }
  }
}

// ---------------- fp32 GEMM (sim2 only): C = A@B ----------------
__global__ __launch_bounds__(256) void gemm_f32(
    const float* __restrict__ A, const float* __restrict__ B,
    float* __restrict__ C, int K, int lda, int ldb, int ldc,
    long long sA, long long sB, long long sC) {
  const int tid = threadIdx.x;
  const int batch = blockIdx.z;
  A += (long long)batch * sA;
  B += (long long)batch * sB;
  C += (long long)batch * sC;
  const int tm = blockIdx.y * 64;
  const int tn = blockIdx.x * 64;

  __shared__ float As[16][65];
  __shared__ float Bs[16][65];

  const int tx = tid & 15, ty = tid >> 4;
  const int ar = tid >> 2, ac = (tid & 3) * 4;
  const int br = tid >> 4, bc = (tid & 15) * 4;

  float acc[4][4];
#pragma unroll
  for (int i = 0; i < 4; ++i)
#pragma unroll
    for (int j = 0; j < 4; ++j) acc[i][j] = 0.f;

  for (int kb = 0; kb < K; kb += 16) {
    const float4 a4 = *(const float4*)(A + (long long)(tm + ar) * lda + kb + ac);
    const float4 b4 = *(const float4*)(B + (long long)(kb + br) * ldb + tn + bc);
    __syncthreads();
    As[ac + 0][ar] = a4.x; As[ac + 1][ar] = a4.y;
    As[ac + 2][ar] = a4.z; As[ac + 3][ar] = a4.w;
    Bs[br][bc + 0] = b4.x; Bs[br][bc + 1] = b4.y;
    Bs[br][bc + 2] = b4.z; Bs[br][bc + 3] = b4.w;
    __syncthreads();
#pragma unroll
    for (int kk = 0; kk < 16; ++kk) {
      float av[4], bv[4];
#pragma unroll
      for (int i = 0; i < 4; ++i) av[i] = As[kk][ty * 4 + i];
#pragma unroll
      for (int j = 0; j < 4; ++j) bv[j] = Bs[kk][tx * 4 + j];
#pragma unroll
      for (int i = 0; i < 4; ++i)
#pragma unroll
        for (int j = 0; j < 4; ++j) acc[i][j] = fmaf(av[i], bv[j], acc[i][j]);
    }
  }
#pragma unroll
  for (int i = 0; i < 4; ++i) {
    const long long r = tm + ty * 4 + i;
#pragma unroll
    for (int j = 0; j < 4; ++j) C[r * ldc + tn + tx * 4 + j] = acc[i][j];
  }
}

// -------- split/hi bf16 MFMA batched GEMM stage body for the pinv chain --------
// v2: B tile (32 cols x K=256 = 16 KB) staged ONCE per block into XOR-swizzled
// LDS via global_load_lds (removes the 4x-redundant per-wave B VMEM loads and
// their L2 latency from the inner loop). Swizzle: linear LDS dest + inverse-
// swizzled global source + same XOR on read (involution, rule both-sides).
// A rows stay direct-from-global (per-wave unique, unroll-prefetched).
static __device__ __forceinline__ void stage_body(
    int tc, int tr, int bh,
    const ushort* __restrict__ Ah, const ushort* __restrict__ Al,
    const ushort* __restrict__ BTh, const ushort* __restrict__ BTl,
    const ushort* __restrict__ D1h, const ushort* __restrict__ D1l,
    const ushort* __restrict__ D2h, const ushort* __restrict__ D2l,
    ushort* __restrict__ Ch, ushort* __restrict__ Cl,
    ushort* __restrict__ CTh, ushort* __restrict__ CTl,
    float alpha, float beta1, float beta2,
    long long sBT, long long sC, int ldc,
    ushort* Bsh, ushort* Bsl,
    ushort (*TBh)[36], ushort (*TBl)[36]) {
  const int tid = threadIdx.x;
  const int wave = tid >> 6, lane = tid & 63;
  const int quad = lane >> 4, l16 = lane & 15;
  const bool hasAl = (Al != nullptr);
  const bool hasBl = (BTl != nullptr);

  const ushort* A_h = Ah + (long long)bh * 65536 + (long long)(tr + wave * 16 + l16) * 256;
  const ushort* A_l = (hasAl ? Al : Ah) + (long long)bh * 65536 +
                      (long long)(tr + wave * 16 + l16) * 256;
  const char* Bg_h = (const char*)(BTh + (long long)bh * sBT + (long long)tc * 256);
  const char* Bg_l = (const char*)((hasBl ? BTl : BTh) + (long long)bh * sBT +
                                   (long long)tc * 256);

  // stage B tile: 4 calls x 4 KB; col = byte>>9, src = lin ^ ((col&7)<<4)
#pragma unroll
  for (int c = 0; c < 4; ++c) {
    const int lin = c * 4096 + tid * 16;
    const int src = lin ^ (((lin >> 9) & 7) << 4);
    char* ldst = (char*)Bsh + c * 4096 + wave * 1024;  // wave-uniform base
    gload_lds16(Bg_h + src, ldst);
    if (hasBl) gload_lds16(Bg_l + src, (char*)Bsl + c * 4096 + wave * 1024);
  }
  __syncthreads();

  f32x4 acc[2];
  acc[0] = (f32x4)0.f; acc[1] = (f32x4)0.f;

#pragma unroll
  for (int kc = 0; kc < 8; ++kc) {
    const int ko = kc * 32 + quad * 8;
    const bf16x8 a_h = *(const bf16x8*)(A_h + ko);
    bf16x8 a_l;
    if (hasAl) a_l = *(const bf16x8*)(A_l + ko);
#pragma unroll
    for (int ct = 0; ct < 2; ++ct) {
      const int col = ct * 16 + l16;
      const int lb = (col * 512 + ko * 2) ^ ((col & 7) << 4);
      const bf16x8 b_h = *(const bf16x8*)((const char*)Bsh + lb);
      acc[ct] = __builtin_amdgcn_mfma_f32_16x16x32_bf16(a_h, b_h, acc[ct], 0, 0, 0);
      if (hasBl) {
        const bf16x8 b_l = *(const bf16x8*)((const char*)Bsl + lb);
        acc[ct] = __builtin_amdgcn_mfma_f32_16x16x32_bf16(a_h, b_l, acc[ct], 0, 0, 0);
      }
      if (hasAl)
        acc[ct] = __builtin_amdgcn_mfma_f32_16x16x32_bf16(a_l, b_h, acc[ct], 0, 0, 0);
    }
  }

#pragma unroll
  for (int ct = 0; ct < 2; ++ct) {
#pragma unroll
    for (int r = 0; r < 4; ++r) {
      const int rl = wave * 16 + quad * 4 + r;
      const int clc = ct * 16 + l16;
      float val = alpha * acc[ct][r];
      if (D1h) {
        const long long di = (long long)bh * 65536 + (long long)(tr + rl) * 256 + tc + clc;
        float d = bf2f(D1h[di]);
        if (D1l) d += bf2f(D1l[di]);
        val += beta1 * d;
      }
      if (D2h) {
        const long long di = (long long)bh * 65536 + (long long)(tr + rl) * 256 + tc + clc;
        float d = bf2f(D2h[di]);
        if (D2l) d += bf2f(D2l[di]);
        val += beta2 * d;
      }
      const ushort h = f2bf(val);
      TBh[rl][clc] = h;
      TBl[rl][clc] = f2bf(val - bf2f(h));
    }
  }
  __syncthreads();
  if (Ch) {  // row-major store, coalesced uint4
    const int rl = tid >> 2, seg = (tid & 3) * 8;
    const long long ci = (long long)bh * sC + (long long)(tr + rl) * ldc + tc + seg;
    *(uint4*)&Ch[ci] = *(const uint4*)&TBh[rl][seg];
    if (Cl) *(uint4*)&Cl[ci] = *(const uint4*)&TBl[rl][seg];
  }
  if (CTh) {  // transposed store: gather 8 from LDS, uint4 out
    const int clc = tid >> 3, seg = (tid & 7) * 8;
    union { uint4 u; ushort s[8]; } th, tl;
#pragma unroll
    for (int j = 0; j < 8; ++j) {
      th.s[j] = TBh[seg + j][clc];
      tl.s[j] = TBl[seg + j][clc];
    }
    const long long gi = (long long)bh * 65536 + (long long)(tc + clc) * 256 + tr + seg;
    *(uint4*)&CTh[gi] = th.u;
    if (CTl) *(uint4*)&CTl[gi] = tl.u;
  }
}

// standard stage kernel: grid (cols/32, rows/64, 16)
__global__ __launch_bounds__(256) void gemm_split(
    const ushort* __restrict__ Ah, const ushort* __restrict__ Al,
    const ushort* __restrict__ BTh, const ushort* __restrict__ BTl,
    const ushort* __restrict__ D1h, const ushort* __restrict__ D1l,
    const ushort* __restrict__ D2h, const ushort* __restrict__ D2l,
    ushort* __restrict__ Ch, ushort* __restrict__ Cl,
    ushort* __restrict__ CTh, ushort* __restrict__ CTl,
    float alpha, float beta1, float beta2,
    long long sBT, long long sC, int ldc) {
  __shared__ __align__(16) ushort Bsh[8192];
  __shared__ __align__(16) ushort Bsl[8192];
  __shared__ ushort TBh[64][36];
  __shared__ ushort TBl[64][36];
  stage_body(blockIdx.x * 32, blockIdx.y * 64, blockIdx.z,
             Ah, Al, BTh, BTl, D1h, D1l, D2h, D2l, Ch, Cl, CTh, CTl,
             alpha, beta1, beta2, sBT, sC, ldc, Bsh, Bsl, TBh, TBl);
}

// dual-update kernel: one launch computes BOTH  z' = -0.25 z@T2 + 3.25 z  and
// Y' = -0.25 Y@T2 + 3.25 Y. grid (8, 8, 16): y<4 -> z rows, y>=4 -> Y rows.
// hasBl always false here -> single B staging buffer.
__global__ __launch_bounds__(256) void gemm_dual(
    const ushort* __restrict__ zA, const ushort* __restrict__ yA,
    const ushort* __restrict__ BT,
    ushort* __restrict__ zC, ushort* __restrict__ zCT,
    ushort* __restrict__ yC, ushort* __restrict__ yCT) {
  __shared__ __align__(16) ushort Bsh[8192];
  __shared__ ushort TBh[64][36];
  __shared__ ushort TBl[64][36];
  const int by = blockIdx.y;
  if (by < 4)
    stage_body(blockIdx.x * 32, by * 64, blockIdx.z,
               zA, nullptr, BT, nullptr, zA, nullptr, nullptr, nullptr,
               zC, nullptr, zCT, nullptr, -0.25f, 3.25f, 0.f,
               65536, 65536, 256, Bsh, Bsh, TBh, TBl);
  else
    stage_body(blockIdx.x * 32, (by - 4) * 64, blockIdx.z,
               yA, nullptr, BT, nullptr, yA, nullptr, nullptr, nullptr,
               yC, nullptr, yCT, nullptr, -0.25f, 3.25f, 0.f,
               65536, 65536, 256, Bsh, Bsh, TBh, TBl);
}

// ------------- landmark means from bf16 q,k -------------
__global__ __launch_bounds__(64) void landmark_kernel(
    const ushort* __restrict__ q, const ushort* __restrict__ k,
    float* __restrict__ qlf, float* __restrict__ klTf,
    ushort* __restrict__ qlb, ushort* __restrict__ klb) {
  const int bh = blockIdx.y, i = blockIdx.x, d = threadIdx.x;
  const long long base = (((long long)bh << 13) + i * 32) * 64 + d;
  float sq = 0.f, sk = 0.f;
#pragma unroll
  for (int j = 0; j < 32; ++j) {
    sq += bf2f(q[base + j * 64]);
    sk += bf2f(k[base + j * 64]);
  }
  const float mq = sq * (1.0f / 32.0f), mk = sk * (1.0f / 32.0f);
  qlf[((long long)bh * 256 + i) * 64 + d] = mq;
  klTf[((long long)bh * 64 + d) * 256 + i] = mk;
  qlb[((long long)bh * 256 + i) * 64 + d] = f2bf(mq);
  klb[((long long)bh * 256 + i) * 64 + d] = f2bf(mk);
}

// ---------------- softmax over rows of length 256: wave per row ----------------
__global__ __launch_bounds__(256) void softmax256(float* __restrict__ a) {
  const long long row = (long long)blockIdx.x * 4 + (threadIdx.x >> 6);
  const int lane = threadIdx.x & 63;
  float* p = a + row * 256 + lane * 4;
  float4 vv = *(float4*)p;
  float m = fmaxf(fmaxf(vv.x, vv.y), fmaxf(vv.z, vv.w));
#pragma unroll
  for (int o = 32; o; o >>= 1) m = fmaxf(m, __shfl_xor(m, o));
  vv.x = __expf(vv.x - m); vv.y = __expf(vv.y - m);
  vv.z = __expf(vv.z - m); vv.w = __expf(vv.w - m);
  float s = vv.x + vv.y + vv.z + vv.w;
#pragma unroll
  for (int o = 32; o; o >>= 1) s += __shfl_xor(s, o);
  const float inv = 1.0f / s;
  vv.x *= inv; vv.y *= inv; vv.z *= inv; vv.w *= inv;
  *(float4*)p = vv;
}

// ---------------- bf16 MFMA flash attention: Out = softmax(Q K^T) V ----------------
// nsplit==1 && CV==null: writes bf16 to Out (ushort*), sO in elements.
// nsplit==1 && CV!=null: fused epilogue -- adds conv residual CV (b,h,n,d) and
//   writes directly into (b*n, 512) layout at Out (ushort*), col block h*64.
__global__ __launch_bounds__(256) void flash_mfma(
    const ushort* __restrict__ Q, const ushort* __restrict__ K,
    const ushort* __restrict__ V, float* __restrict__ Out,
    const ushort* __restrict__ CV,
    float* __restrict__ Opart, float* __restrict__ Mpart,
    float* __restrict__ Lpart,
    long long sQ, long long sK, long long sV, long long sO,
    int iters, int nsplit) {
  const int bh = blockIdx.z, mt = blockIdx.y, ns = blockIdx.x;
  const int tid = threadIdx.x;
  const int wave = tid >> 6, lane = tid & 63;
  const int quad = lane >> 4, l16 = lane & 15;
  __shared__ ushort Vt[64][72];  // [d][key]
  __shared__ ushort Ps[64][72];  // [q-row][key]

  const ushort* Qb = Q + (long long)bh * sQ + (long long)(mt * 64) * 64;
  const ushort* Kb = K + (long long)bh * sK + (long long)(ns * iters * 64) * 64;
  const ushort* Vb = V + (long long)bh * sV + (long long)(ns * iters * 64) * 64;

  bf16x8 aq[2];
#pragma unroll
  for (int kc = 0; kc < 2; ++kc)
    aq[kc] = *(const bf16x8*)(Qb + (long long)(wave * 16 + l16) * 64 + kc * 32 + quad * 8);

  f32x4 acc[4];
  float mrow[4], lrow[4];
#pragma unroll
  for (int dt = 0; dt < 4; ++dt) acc[dt] = (f32x4)0.f;
#pragma unroll
  for (int r = 0; r < 4; ++r) { mrow[r] = -1e30f; lrow[r] = 0.f; }

  for (int it = 0; it < iters; ++it) {
    __syncthreads();
    for (int i = tid; i < 512; i += 256) {
      const int key = i & 63, c8 = (i >> 6) * 8;
      union { uint4 u; ushort s[8]; } t;
      t.u = *(const uint4*)(Vb + (long long)(it * 64 + key) * 64 + c8);
#pragma unroll
      for (int j = 0; j < 8; ++j) Vt[c8 + j][key] = t.s[j];
    }
    f32x4 sfr[4];
#pragma unroll
    for (int kt = 0; kt < 4; ++kt) {
      sfr[kt] = (f32x4)0.f;
#pragma unroll
      for (int kc = 0; kc < 2; ++kc) {
        const bf16x8 bk = *(const bf16x8*)(Kb +
            (long long)(it * 64 + kt * 16 + l16) * 64 + kc * 32 + quad * 8);
        sfr[kt] = __builtin_amdgcn_mfma_f32_16x16x32_bf16(aq[kc], bk, sfr[kt], 0, 0, 0);
      }
    }
#pragma unroll
    for (int r = 0; r < 4; ++r) {
      float rm = fmaxf(fmaxf(sfr[0][r], sfr[1][r]), fmaxf(sfr[2][r], sfr[3][r]));
#pragma unroll
      for (int off = 1; off < 16; off <<= 1) rm = fmaxf(rm, __shfl_xor(rm, off));
      const float mn = fmaxf(mrow[r], rm);
      const float scv = __expf(mrow[r] - mn);
      float rs = 0.f;
#pragma unroll
      for (int kt = 0; kt < 4; ++kt) {
        const float p = __expf(sfr[kt][r] - mn);
        sfr[kt][r] = p;
        rs += p;
      }
#pragma unroll
      for (int off = 1; off < 16; off <<= 1) rs += __shfl_xor(rs, off);
      lrow[r] = lrow[r] * scv + rs;
      mrow[r] = mn;
#pragma unroll
      for (int dt = 0; dt < 4; ++dt) acc[dt][r] *= scv;
#pragma unroll
      for (int kt = 0; kt < 4; ++kt)
        Ps[wave * 16 + quad * 4 + r][kt * 16 + l16] = f2bf(sfr[kt][r]);
    }
    __syncthreads();
#pragma unroll
    for (int kc = 0; kc < 2; ++kc) {
      const bf16x8 ap = *(const bf16x8*)&Ps[wave * 16 + l16][kc * 32 + quad * 8];
#pragma unroll
      for (int dt = 0; dt < 4; ++dt) {
        const bf16x8 bv = *(const bf16x8*)&Vt[dt * 16 + l16][kc * 32 + quad * 8];
        acc[dt] = __builtin_amdgcn_mfma_f32_16x16x32_bf16(ap, bv, acc[dt], 0, 0, 0);
      }
    }
  }

  if (nsplit == 1) {
    if (CV) {  // fused: add conv residual, write (b*n, 512) layout
      const int b = bh >> 3, h = bh & 7;
      const ushort* cvb = CV + (((long long)bh << 13) + mt * 64) * 64;
      ushort* Ob = (ushort*)Out + ((long long)(b * 8192 + mt * 64)) * 512 + h * 64;
#pragma unroll
      for (int r = 0; r < 4; ++r) {
        const float inv = 1.0f / lrow[r];
        const int row = wave * 16 + quad * 4 + r;
#pragma unroll
        for (int dt = 0; dt < 4; ++dt) {
          const int col = dt * 16 + l16;
          const float val = acc[dt][r] * inv + bf2f(cvb[(long long)row * 64 + col]);
          Ob[(long long)row * 512 + col] = f2bf(val);
        }
      }
    } else {
      ushort* Ob = (ushort*)Out + (long long)bh * sO + (long long)(mt * 64) * 64;
#pragma unroll
      for (int r = 0; r < 4; ++r) {
        const float inv = 1.0f / lrow[r];
        const int row = wave * 16 + quad * 4 + r;
#pragma unroll
        for (int dt = 0; dt < 4; ++dt)
          Ob[(long long)row * 64 + dt * 16 + l16] = f2bf(acc[dt][r] * inv);
      }
    }
  } else {
    const long long pbase = ((long long)(bh * gridDim.y + mt) * nsplit + ns);
    const int row0 = wave * 16 + quad * 4;
#pragma unroll
    for (int r = 0; r < 4; ++r) {
#pragma unroll
      for (int dt = 0; dt < 4; ++dt)
        Opart[(pbase * 64 + row0 + r) * 64 + dt * 16 + l16] = acc[dt][r];
      if (l16 == 0) {
        Mpart[pbase * 64 + row0 + r] = mrow[r];
        Lpart[pbase * 64 + row0 + r] = lrow[r];
      }
    }
  }
}

// ------- merge flash partials -> a3v^T hi/lo bf16 [bh][64][256]; 1024 blocks -------
__global__ __launch_bounds__(256) void flash_merge(
    const float* __restrict__ Opart, const float* __restrict__ Mpart,
    const float* __restrict__ Lpart, ushort* __restrict__ a3vTh,
    ushort* __restrict__ a3vTl, int nsplit) {
  const int bm = blockIdx.x >> 4;  // bh*4 + mt
  const int rg = blockIdx.x & 15;  // 4-row group
  const int bh = bm >> 2, mt = bm & 3;
  const int c = threadIdx.x & 63, rb = threadIdx.x >> 6;
  const int r = rg * 4 + rb;
  float ms = -1e30f;
  for (int ns = 0; ns < nsplit; ++ns)
    ms = fmaxf(ms, Mpart[(bm * nsplit + ns) * 64 + r]);
  float L = 0.f, O = 0.f;
  for (int ns = 0; ns < nsplit; ++ns) {
    const float w = __expf(Mpart[(bm * nsplit + ns) * 64 + r] - ms);
    L += w * Lpart[(bm * nsplit + ns) * 64 + r];
    O += w * Opart[((long long)(bm * nsplit + ns) * 64 + r) * 64 + c];
  }
  const float val = O / L;
  const ushort h = f2bf(val);
  const long long ti = (long long)bh * 16384 + (long long)c * 256 + mt * 64 + r;
  a3vTh[ti] = h;
  a3vTl[ti] = f2bf(val - bf2f(h));
}

// ------- pm init + a2 row/col-sum global maxes (atomicMax on positive floats) -------
__global__ void pm_init(float* __restrict__ pm) {
  if (threadIdx.x < 2) pm[threadIdx.x] = 0.f;
}

__global__ __launch_bounds__(256) void a2_sums(const float* __restrict__ a2,
                                               float* __restrict__ pm) {
  // grid (8, 16): p = 32-row/col slice, bh
  const int p = blockIdx.x, bh = blockIdx.y;
  const float* m = a2 + (long long)bh * 65536;
  const int tid = threadIdx.x;
  __shared__ float red[4];
  {  // row sums: 8 threads per row, 32 elems each
    const int r = p * 32 + (tid >> 3);
    const int c0 = (tid & 7) * 32;
    float s = 0.f;
#pragma unroll 8
    for (int j = 0; j < 32; ++j) s += m[r * 256 + c0 + j];
    s += __shfl_xor(s, 1); s += __shfl_xor(s, 2); s += __shfl_xor(s, 4);
    float mx = s;
#pragma unroll
    for (int o = 8; o < 64; o <<= 1) mx = fmaxf(mx, __shfl_xor(mx, o));
    if ((tid & 63) == 0) red[tid >> 6] = mx;
    __syncthreads();
    if (tid == 0) {
      mx = fmaxf(fmaxf(red[0], red[1]), fmaxf(red[2], red[3]));
      atomicMax((int*)&pm[0], __float_as_int(mx));
    }
    __syncthreads();
  }
  {  // col sums: 8 threads per col, 32 rows each
    const int c = p * 32 + (tid >> 3);
    const int r0 = (tid & 7) * 32;
    float s = 0.f;
#pragma unroll 8
    for (int j = 0; j < 32; ++j) s += m[(r0 + j) * 256 + c];
    s += __shfl_xor(s, 1); s += __shfl_xor(s, 2); s += __shfl_xor(s, 4);
    float mx = s;
#pragma unroll
    for (int o = 8; o < 64; o <<= 1) mx = fmaxf(mx, __shfl_xor(mx, o));
    if ((tid & 63) == 0) red[tid >> 6] = mx;
    __syncthreads();
    if (tid == 0) {
      mx = fmaxf(fmaxf(red[0], red[1]), fmaxf(red[2], red[3]));
      atomicMax((int*)&pm[1], __float_as_int(mx));
    }
  }
}

// ---- pinv init: split a2 -> hi/lo; z0 = a2^T * s (hi row-major + hi transposed) ----
__global__ __launch_bounds__(256) void pinv_init(
    const float* __restrict__ a2, const float* __restrict__ pm,
    ushort* __restrict__ a2h, ushort* __restrict__ a2l,
    ushort* __restrict__ zh, ushort* __restrict__ zTh) {
  const int bh = blockIdx.y;
  const float s = 1.0f / (pm[0] * pm[1]);
  const long long base = (long long)bh * 65536;
  const int i0 = blockIdx.x * 4096;
  for (int t = threadIdx.x; t < 4096; t += 256) {
    const int idx = i0 + t;
    const float v = a2[base + idx];
    const ushort h = f2bf(v);
    a2h[base + idx] = h;
    a2l[base + idx] = f2bf(v - bf2f(h));
    zTh[base + idx] = f2bf(v * s);  // zT = a2 * s
    const float vt = a2[base + ((long long)(idx & 255) << 8) + (idx >> 8)] * s;
    zh[base + idx] = f2bf(vt);
  }
}

// -------- depthwise conv (KS=33) from bf16 v -> cv (bf16, (b,h,n,d)) --------
__global__ __launch_bounds__(256) void conv_store(const ushort* __restrict__ v,
                                                  const float* __restrict__ w,
                                                  ushort* __restrict__ cv) {
  const int bh = blockIdx.y;
  const int n0 = blockIdx.x * 128;
  const int h = bh & 7;
  __shared__ float vs[160][64];
  __shared__ float ws[33];
  if (threadIdx.x < 33) ws[threadIdx.x] = w[h * 33 + threadIdx.x];
  for (int i = threadIdx.x; i < 160 * 8; i += 256) {
    const int r = i >> 3, c8 = (i & 7) * 8;
    const int n = n0 - 16 + r;
    if (n >= 0 && n < 8192) {
      union { uint4 u; ushort s[8]; } t;
      t.u = *(const uint4*)(v + (((long long)bh << 13) + n) * 64 + c8);
#pragma unroll
      for (int j = 0; j < 8; ++j) vs[r][c8 + j] = bf2f(t.s[j]);
    } else {
#pragma unroll
      for (int j = 0; j < 8; ++j) vs[r][c8 + j] = 0.f;
    }
  }
  __syncthreads();
  const int d = threadIdx.x & 63, r0 = threadIdx.x >> 6;
  for (int rr = r0; rr < 128; rr += 4) {
    float acc = 0.f;
#pragma unroll
    for (int kk = 0; kk < 33; ++kk) acc += ws[kk] * vs[rr + kk][d];
    cv[(((long long)bh << 13) + n0 + rr) * 64 + d] = f2bf(acc);
  }
}

// ---------------- host ----------------
static inline void launch_split(hipStream_t st, int gridX,
    const ushort* Ah, const ushort* Al,
    const ushort* BTh, const ushort* BTl, long long sBT,
    const ushort* D1h, const ushort* D1l, float beta1,
    const ushort* D2h, const ushort* D2l, float beta2,
    ushort* Ch, ushort* Cl, ushort* CTh, ushort* CTl,
    long long sC, int ldc, float alpha) {
  dim3 grid((unsigned)gridX, 4, 16);
  hipLaunchKernelGGL(gemm_split, grid, dim3(256), 0, st, Ah, Al, BTh, BTl,
                     D1h, D1l, D2h, D2l, Ch, Cl, CTh, CTl,
                     alpha, beta1, beta2, sBT, sC, ldc);
}

extern "C" void kernel_launch(void* const* d_in, const int* in_sizes, int n_in,
                              void* d_out, int out_size, void* d_ws, size_t ws_size,
                              hipStream_t stream) {
  const float* x = (const float*)d_in[0];
  // d_in[1] = mask: all-true -> unused
  const float* ln_w = (const float*)d_in[2];
  const float* ln_b = (const float*)d_in[3];
  const float* w_qkv = (const float*)d_in[4];
  const float* w_out = (const float*)d_in[5];
  const float* b_out = (const float*)d_in[6];
  const float* conv_w = (const float*)d_in[7];
  float* out = (float*)d_out;

  float* ws = (float*)d_ws;
  // Region R (10,485,760 floats = 40 MB), time-multiplexed:
  //   phase A: Opart/Mpart/Lpart; phase B: pinv chain; phase C: ao2 + cv (bf16)
  float* R = ws;
  float* a2   = R + 10485760LL;        // 1048576 fp32
  float* qlf  = a2 + 1048576LL;        // 262144
  float* klTf = qlf + 262144LL;        // 262144
  float* pm   = klTf + 262144LL;       // 64
  ushort* q_bf   = (ushort*)(pm + 64); // 8388608 each
  ushort* k_bf   = q_bf + 8388608LL;
  ushort* v_bf   = k_bf + 8388608LL;
  ushort* xn_bf  = v_bf + 8388608LL;
  ushort* ql_bf  = xn_bf + 8388608LL;  // 262144
  ushort* kl_bf  = ql_bf + 262144LL;
  ushort* tb_bf  = kl_bf + 262144LL;   // 262144
  ushort* wqT_bf = tb_bf + 262144LL;   // 786432
  ushort* woT_bf = wqT_bf + 786432LL;  // 262144
  ushort* a2h    = woT_bf + 262144LL;  // 1048576 each
  ushort* a2l    = a2h + 1048576LL;
  ushort* a3vTh  = a2l + 1048576LL;    // 262144 each
  ushort* a3vTl  = a3vTh + 262144LL;

  // phase A (nsplit=16): Opart 4,194,304 fp32 (16 MB) + M/L 65,536 each
  float* Opart = R;
  float* Mpart = R + 4194304LL;
  float* Lpart = R + 4194304LL + 65536;
  // phase B: chain arrays (each 1,048,576 ushorts)
  ushort* cb = (ushort*)R;
  ushort* zah = cb;                ushort* zal = cb + 1048576LL;
  ushort* zaTh = cb + 2097152LL;
  ushort* zbh = cb + 4194304LL;
  ushort* zbTh = cb + 6291456LL;
  ushort* Ph = cb + 8388608LL;     ushort* Pl = cb + 9437184LL;
  ushort* PTh = cb + 10485760LL;   ushort* PTl = cb + 11534336LL;
  ushort* P2h = cb + 12582912LL;   ushort* P2l = cb + 13631488LL;
  ushort* P2Th = cb + 14680064LL;  ushort* P2Tl = cb + 15728640LL;
  ushort* T2Th = cb + 18874368LL;  ushort* T2Tl = cb + 19922944LL;
  // Y recurrence buffers (hi-only iters): live in lo-regions unused before split
  ushort* Yah = Pl;    ushort* YaTh = PTl;
  ushort* Ybh = P2l;   ushort* YbTh = P2Tl;
  // phase C: fused attn output (b*n,512) + conv buffer
  ushort* ao2_bf = (ushort*)R;                  // 8388608 ushorts
  ushort* cv_bf  = (ushort*)R + 8388608LL;      // 8388608 ushorts

  // 0. weight transposes + bf16 convert
  hipLaunchKernelGGL(convert_T_bf16, dim3(3072), dim3(256), 0, stream,
                     w_qkv, wqT_bf, 512, 1536);
  hipLaunchKernelGGL(convert_T_bf16, dim3(1024), dim3(256), 0, stream,
                     w_out, woT_bf, 512, 512);
  // 1. LayerNorm -> bf16
  hipLaunchKernelGGL(ln_kernel, dim3(16384), dim3(256), 0, stream, x, ln_w, ln_b, xn_bf);
  // 2. qkv GEMM (MFMA, 8-wave), scatter q(x0.125),k,v as bf16 (b,h,n,d)
  hipLaunchKernelGGL(gemm_bf16, dim3(12, 128), dim3(512), 0, stream,
                     xn_bf, wqT_bf, nullptr, q_bf, k_bf, v_bf, nullptr, nullptr, 512, 2);
  // 3. landmarks
  hipLaunchKernelGGL(landmark_kernel, dim3(256, 16), dim3(64), 0, stream,
                     q_bf, k_bf, qlf, klTf, ql_bf, kl_bf);
  // 4. sim2 = ql @ klT -> a2 (fp32) ; softmax
  {
    dim3 g(4, 4, 16);
    hipLaunchKernelGGL(gemm_f32, g, dim3(256), 0, stream, qlf, klTf, a2,
                       64, 64, 256, 256, 16384LL, 16384LL, 65536LL);
  }
  hipLaunchKernelGGL(softmax256, dim3(1024), dim3(256), 0, stream, a2);
  // 5. a3v = softmax(ql @ k^T) @ v  -- MFMA flash, nsplit=16 (4 blocks/CU), merge
  hipLaunchKernelGGL(flash_mfma, dim3(16, 4, 16), dim3(256), 0, stream,
                     ql_bf, k_bf, v_bf, (float*)nullptr, (const ushort*)nullptr,
                     Opart, Mpart, Lpart,
                     16384LL, 524288LL, 524288LL, 0LL, 8, 16);
  hipLaunchKernelGGL(flash_merge, dim3(1024), dim3(256), 0, stream,
                     Opart, Mpart, Lpart, a3vTh, a3vTl, 16);
  // 6. pinv of a2 via Newton-Schulz; Y-recurrence saves the per-iter a2@z launch
  hipLaunchKernelGGL(pm_init, dim3(1), dim3(64), 0, stream, pm);
  hipLaunchKernelGGL(a2_sums, dim3(8, 16), dim3(256), 0, stream, a2, pm);
  hipLaunchKernelGGL(pinv_init, dim3(16, 16), dim3(256), 0, stream, a2, pm,
                     a2h, a2l, zah, zaTh);
  // Y0 = a2 @ z0
  launch_split(stream, 8, a2h, nullptr, zaTh, nullptr, 65536,
               nullptr, nullptr, 0.f, nullptr, nullptr, 0.f,
               Yah, nullptr, YaTh, nullptr, 65536, 256, 1.f);
  {
    ushort *zh = zah, *zTh = zaTh, *zwh = zbh, *zwTh = zbTh;
    ushort *Yh = Yah, *YTh = YaTh, *Ywh = Ybh, *YwTh = YbTh;
    for (int it = 0; it < 5; ++it) {
      // P2 = Y^2
      launch_split(stream, 8, Yh, nullptr, YTh, nullptr, 65536,
                   nullptr, nullptr, 0.f, nullptr, nullptr, 0.f,
                   P2h, nullptr, P2Th, nullptr, 65536, 256, 1.f);
      // T2 = Y@P2 + 15Y - 7P2 (transposed out)
      launch_split(stream, 8, Yh, nullptr, P2Th, nullptr, 65536,
                   Yh, nullptr, 15.f, P2h, nullptr, -7.f,
                   nullptr, nullptr, T2Th, nullptr, 65536, 256, 1.f);
      if (it < 4) {  // dual update: z' and Y' in one launch
        hipLaunchKernelGGL(gemm_dual, dim3(8, 8, 16), dim3(256), 0, stream,
                           zh, Yh, T2Th, zwh, zwTh, Ywh, YwTh);
        ushort* t;
        t = zh; zh = zwh; zwh = t;  t = zTh; zTh = zwTh; zwTh = t;
        t = Yh; Yh = Ywh; Ywh = t;  t = YTh; YTh = YwTh; YwTh = t;
      } else {       // last hi iter: z-only update (Y no longer needed)
        launch_split(stream, 8, zh, nullptr, T2Th, nullptr, 65536,
                     zh, nullptr, 3.25f, nullptr, nullptr, 0.f,
                     zwh, nullptr, zwTh, nullptr, 65536, 256, -0.25f);
      }
    }
  }
  // final iteration: full split precision, fresh P = a2@z5 (z5 = zbh/zbTh)
  launch_split(stream, 8, a2h, a2l, zbTh, nullptr, 65536,
               nullptr, nullptr, 0.f, nullptr, nullptr, 0.f,
               Ph, Pl, PTh, PTl, 65536, 256, 1.f);
  launch_split(stream, 8, Ph, Pl, PTh, PTl, 65536,
               nullptr, nullptr, 0.f, nullptr, nullptr, 0.f,
               P2h, P2l, P2Th, P2Tl, 65536, 256, 1.f);
  launch_split(stream, 8, Ph, Pl, P2Th, P2Tl, 65536,
               Ph, Pl, 15.f, P2h, P2l, -7.f,
               nullptr, nullptr, T2Th, T2Tl, 65536, 256, 1.f);
  launch_split(stream, 8, zbh, nullptr, T2Th, T2Tl, 65536,
               zbh, nullptr, 3.25f, nullptr, nullptr, 0.f,
               zah, zal, nullptr, nullptr, 65536, 256, -0.25f);
  // 7. tb = z6 @ a3v  (split; hi-only bf16 output)
  launch_split(stream, 2, zah, zal, a3vTh, a3vTl, 16384,
               nullptr, nullptr, 0.f, nullptr, nullptr, 0.f,
               tb_bf, nullptr, nullptr, nullptr, 16384, 64, 1.f);
  // 8. depthwise conv residual -> cv (bf16); overwrites dead P-region of chain
  hipLaunchKernelGGL(conv_store, dim3(64, 16), dim3(256), 0, stream, v_bf, conv_w, cv_bf);
  // 9. out1 = softmax(q @ kl^T) @ tb  -- MFMA flash, fused +cv, (b*n,512) bf16 out
  hipLaunchKernelGGL(flash_mfma, dim3(1, 128, 16), dim3(256), 0, stream,
                     q_bf, kl_bf, tb_bf, (float*)ao2_bf, cv_bf,
                     (float*)nullptr, (float*)nullptr, (float*)nullptr,
                     524288LL, 16384LL, 16384LL, 0LL, 4, 1);
  // 10. final: out = ao2 @ w_out + b_out + x (MFMA, 8-wave)
  hipLaunchKernelGGL(gemm_bf16, dim3(4, 128), dim3(512), 0, stream,
                     ao2_bf, woT_bf, out, nullptr, nullptr, nullptr, b_out, x, 512, 3);
}